// Round 1
// 567.505 us; speedup vs baseline: 1.2972x; 1.2972x over previous
//
#include <hip/hip_runtime.h>
#include <float.h>
#include <limits.h>

// Problem constants
#define BB 16384   // batch rows
#define DIN 1024   // encoder input dim
#define CB 512     // codebook dim
#define KC 1024    // codewords per layer
#define NL 4       // layers

// Refine margin: fp16 1-term distance noise std ~0.022, max ~0.13.
// 0.25 = ~8 sigma AND >= 2x max single-value error (certainty bound).
#define DELTA 0.25f

typedef __attribute__((ext_vector_type(8))) _Float16 half8;
typedef __attribute__((ext_vector_type(8))) short bf16x8;
typedef __attribute__((ext_vector_type(8))) unsigned short us8;
typedef __attribute__((ext_vector_type(4))) float f32x4;

__device__ __forceinline__ unsigned short f2h(float f) {
  _Float16 h = (_Float16)f;  // RTN
  return *(unsigned short*)&h;
}

// fp32 -> bf16 RTNE (inputs are finite random normals; no NaN handling needed)
__device__ __forceinline__ unsigned short f2b(float f) {
  unsigned u = __float_as_uint(f);
  unsigned r = u + 0x7fffu + ((u >> 16) & 1u);
  return (unsigned short)(r >> 16);
}
__device__ __forceinline__ float b2f(unsigned short h) {
  return __uint_as_float(((unsigned)h) << 16);
}

// Staged layout (shorts) for matrix M[rows][512]:
//   off(row,k) = ((row>>4)*16 + (k>>5))*512 + (((k>>3)&3)*16 + (row&15))*8 + (k&7)
// = MFMA A/B fragment lane image; staging = contiguous 1KB loads.
__device__ __forceinline__ size_t staged_off(int row, int k) {
  return ((size_t)(row >> 4) * 16 + (k >> 5)) * 512 +
         (((k >> 3) & 3) * 16 + (row & 15)) * 8 + (k & 7);
}

// Same staged scheme for 1024-wide rows (WT matrices: [512 rows][1024 k]).
__device__ __forceinline__ size_t staged_off_w(int row, int k) {
  return ((size_t)(row >> 4) * 32 + (k >> 5)) * 512 +
         (((k >> 3) & 3) * 16 + (row & 15)) * 8 + (k & 7);
}

// ---------------------------------------------------------------------------
// Codebooks -> fp16, staged layout.
// ---------------------------------------------------------------------------
__global__ __launch_bounds__(256) void cbsplit_kernel(
    const float* __restrict__ cbs, unsigned short* __restrict__ Ch16) {
  int g = (blockIdx.x * 256 + threadIdx.x) * 4;  // flat over NL*KC*CB
  int k = g & (CB - 1);
  int lr = g >> 9;
  int layer = lr >> 10, row = lr & (KC - 1);
  float4 v = *(const float4*)(cbs + g);
  size_t off = (size_t)layer * (KC / 16) * 8192 + staged_off(row, k);
  *(ushort4*)(Ch16 + off) = make_ushort4(f2h(v.x), f2h(v.y), f2h(v.z), f2h(v.w));
}

// ---------------------------------------------------------------------------
// Residual -> fp16, staged layout (after enc_gemm).
// ---------------------------------------------------------------------------
__global__ __launch_bounds__(256) void rsplit_kernel(
    const float* __restrict__ R, unsigned short* __restrict__ Rh16) {
  int g = (blockIdx.x * 256 + threadIdx.x) * 4;
  int k = g & (CB - 1);
  int row = g >> 9;
  float4 v = *(const float4*)(R + g);
  size_t off = staged_off(row, k);
  *(ushort4*)(Rh16 + off) = make_ushort4(f2h(v.x), f2h(v.y), f2h(v.z), f2h(v.w));
}

// ---------------------------------------------------------------------------
// enc_W^T -> bf16 hi/lo split, staged layout. WTh/WTm are [512][1024] staged.
// W is [DIN=1024][CB=512] row-major fp32; we store its transpose.
// ---------------------------------------------------------------------------
__global__ __launch_bounds__(256) void wsplit_kernel(
    const float* __restrict__ W, unsigned short* __restrict__ WTh,
    unsigned short* __restrict__ WTm) {
  int g = blockIdx.x * 256 + threadIdx.x;  // 131072 total
  int n = g >> 8;           // 0..511  (col of W = row of WT)
  int k0 = (g & 255) * 4;   // 0..1020 (row of W), 4-aligned -> same 8-chunk
  ushort4 h4, m4;
  unsigned short* hp = (unsigned short*)&h4;
  unsigned short* mp = (unsigned short*)&m4;
#pragma unroll
  for (int i = 0; i < 4; ++i) {
    float x = W[(size_t)(k0 + i) * CB + n];
    unsigned short h = f2b(x);
    hp[i] = h;
    mp[i] = f2b(x - b2f(h));
  }
  size_t off = staged_off_w(n, k0);
  *(ushort4*)(WTh + off) = h4;
  *(ushort4*)(WTm + off) = m4;
}

// ---------------------------------------------------------------------------
// cnorm[l*KC+k] = ||codebooks[l][k]||^2, fp64 (refine) + fp32 (stage1)
// ---------------------------------------------------------------------------
__global__ __launch_bounds__(256) void cnorm_kernel(
    const float* __restrict__ cbs, double* __restrict__ cnorm,
    float* __restrict__ cnormF) {
  int gw = (blockIdx.x * blockDim.x + threadIdx.x) >> 6;
  int lane = threadIdx.x & 63;
  if (gw >= NL * KC) return;
  const float* row = cbs + (size_t)gw * CB;
  double s = 0.0;
  for (int i = lane; i < CB; i += 64) {
    double v = (double)row[i];
    s += v * v;
  }
#pragma unroll
  for (int off = 32; off > 0; off >>= 1)
    s += __shfl_down(s, off, 64);
  if (lane == 0) { cnorm[gw] = s; cnormF[gw] = (float)s; }
}

// ---------------------------------------------------------------------------
// Encoder GEMM: R = X @ W + b via 2-way bf16 split, 4 cross products on the
// bf16 MFMA pipe (replaces the fp64-MFMA version: 59.6 TF fp64-pipe-bound).
//   X = Xh + Xm (split in-register per k-chunk), WT = WTh + WTm (pre-split,
//   staged, loaded via global_load_lds).  acc += Ah*Bh + Ah*Bm + Am*Bh + Am*Bm.
// 128x128 tile, BK=32, 4 waves, structure cloned from vq_stage1 (verified
// fragment/staged layout).  Dropped terms <= 2^-18-order => R error ~2.4e-6,
// below the reference's own fp32 ||c||^2 noise (~3.4e-4 on distances).
// ---------------------------------------------------------------------------
__global__ __launch_bounds__(256, 2) void enc_gemm(
    const float* __restrict__ X, const unsigned short* __restrict__ WTh,
    const unsigned short* __restrict__ WTm, const float* __restrict__ bias,
    float* __restrict__ R) {
  __shared__ __align__(16) char lds[32768];  // Ah 8K | Am 8K | Bh 8K | Bm 8K
  int tid = threadIdx.x;
  int wave = tid >> 6, lane = tid & 63;
  int wm = wave >> 1, wn = wave & 1;
  int q = lane >> 4, l15 = lane & 15;
  // XCD swizzle: 512 blocks; each XCD gets 16 consecutive row-panels x 4
  // col-blocks -> the 4 blocks sharing an X row-panel are co-resident.
  int swz = (blockIdx.x & 7) * 64 + (blockIdx.x >> 3);
  int rb = swz >> 2, cbk = swz & 3;
  int row0 = rb * 128, n0 = cbk * 128;

  // A staging map: thread -> (local row ar, k-quarter aq)
  int ar = tid >> 1;          // 0..127
  int aq = (tid & 1) * 16;    // 0 or 16
  const float* xsrc = X + (size_t)(row0 + ar) * DIN + aq;
  // A LDS write base (bytes): chunk (ar>>4) of 1KB; within: ((aq/8)*16+r15)*16
  char* aw_h = lds + (ar >> 4) * 1024 + (((aq >> 3) & 3) * 16 + (ar & 15)) * 16;
  char* aw_m = aw_h + 8192;

  f32x4 acc[4][4];
#pragma unroll
  for (int i = 0; i < 4; ++i)
#pragma unroll
    for (int j = 0; j < 4; ++j)
      acc[i][j] = (f32x4){0.f, 0.f, 0.f, 0.f};

  // prologue: load + split k-chunk 0
  float xv[16];
  unsigned short hv[16], mv[16];
#pragma unroll
  for (int j = 0; j < 4; ++j) {
    float4 v = *(const float4*)(xsrc + j * 4);
    xv[4 * j + 0] = v.x; xv[4 * j + 1] = v.y;
    xv[4 * j + 2] = v.z; xv[4 * j + 3] = v.w;
  }
#pragma unroll
  for (int j = 0; j < 16; ++j) {
    unsigned short h = f2b(xv[j]);
    hv[j] = h;
    mv[j] = f2b(xv[j] - b2f(h));
  }

  for (int kt = 0; kt < 32; ++kt) {
    __syncthreads();  // previous iteration's fragment reads done
    // A tiles: ds_write from the regs split during the previous MFMA phase
    us8 h0, h1, m0, m1;
#pragma unroll
    for (int e = 0; e < 8; ++e) {
      h0[e] = (short)hv[e]; h1[e] = (short)hv[8 + e];
      m0[e] = (short)mv[e]; m1[e] = (short)mv[8 + e];
    }
    *(us8*)aw_h = h0; *(us8*)(aw_h + 256) = h1;
    *(us8*)aw_m = m0; *(us8*)(aw_m + 256) = m1;
    // B tiles: each wave stages 4 of the 16 1KB chunks (Bh: 0..7, Bm: 8..15)
#pragma unroll
    for (int i = 0; i < 4; ++i) {
      int c = wave * 4 + i;
      const unsigned short* bsrc = (c < 8) ? WTh : WTm;
      int rg = (n0 >> 4) + (c & 7);
      __builtin_amdgcn_global_load_lds(
          (const __attribute__((address_space(1))) void*)(
              bsrc + ((size_t)rg * 32 + kt) * 512 + lane * 8),
          (__attribute__((address_space(3))) void*)(lds + 16384 + c * 1024),
          16, 0, 0);
    }
    __syncthreads();  // tiles ready (drains lgkm + vm)

    // fragment reads
    bf16x8 ah[4], am[4];
#pragma unroll
    for (int ti = 0; ti < 4; ++ti) {
      ah[ti] = *(const bf16x8*)(lds + (wm * 4 + ti) * 1024 + lane * 16);
      am[ti] = *(const bf16x8*)(lds + 8192 + (wm * 4 + ti) * 1024 + lane * 16);
    }
    // issue next A chunk's global loads; they complete under the MFMAs
    int kn = (kt + 1) & 31;
#pragma unroll
    for (int j = 0; j < 4; ++j) {
      float4 v = *(const float4*)(xsrc + kn * 32 + j * 4);
      xv[4 * j + 0] = v.x; xv[4 * j + 1] = v.y;
      xv[4 * j + 2] = v.z; xv[4 * j + 3] = v.w;
    }
#pragma unroll
    for (int tj = 0; tj < 4; ++tj) {
      bf16x8 bh = *(const bf16x8*)(lds + 16384 + (wn * 4 + tj) * 1024 + lane * 16);
      bf16x8 bm = *(const bf16x8*)(lds + 24576 + (wn * 4 + tj) * 1024 + lane * 16);
#pragma unroll
      for (int ti = 0; ti < 4; ++ti) {
        acc[ti][tj] = __builtin_amdgcn_mfma_f32_16x16x32_bf16(ah[ti], bh, acc[ti][tj], 0, 0, 0);
        acc[ti][tj] = __builtin_amdgcn_mfma_f32_16x16x32_bf16(am[ti], bh, acc[ti][tj], 0, 0, 0);
        acc[ti][tj] = __builtin_amdgcn_mfma_f32_16x16x32_bf16(ah[ti], bm, acc[ti][tj], 0, 0, 0);
        acc[ti][tj] = __builtin_amdgcn_mfma_f32_16x16x32_bf16(am[ti], bm, acc[ti][tj], 0, 0, 0);
      }
    }
    // split next chunk (VALU; overlaps/follows MFMAs, consumed after barrier)
#pragma unroll
    for (int j = 0; j < 16; ++j) {
      unsigned short h = f2b(xv[j]);
      hv[j] = h;
      mv[j] = f2b(xv[j] - b2f(h));
    }
  }

  // Epilogue: verified 16x16 C/D mapping (col = l15, row = q*4 + r)
#pragma unroll
  for (int ti = 0; ti < 4; ++ti) {
#pragma unroll
    for (int tj = 0; tj < 4; ++tj) {
      int col = n0 + wn * 64 + tj * 16 + l15;
      float bv = bias[col];
#pragma unroll
      for (int r = 0; r < 4; ++r) {
        int row = row0 + wm * 64 + ti * 16 + q * 4 + r;
        R[(size_t)row * CB + col] = acc[ti][tj][r] + bv;
      }
    }
  }
}

// ---------------------------------------------------------------------------
// Stage 1: 1-term fp16 MFMA distance GEMM, 128x128 tile, BK=32.
// S = fp16(R) . fp16(C), fp32 acc; d = cnormF - 2S; per-row top-2 per
// 128-col block -> cand. Staging: 2 matrices, 1KB contiguous loads.
// ---------------------------------------------------------------------------
__global__ __launch_bounds__(256) void vq_stage1(
    const unsigned short* __restrict__ Rh16,
    const unsigned short* __restrict__ Ch16,
    const float* __restrict__ cnormF, float4* __restrict__ cand) {
  __shared__ __align__(16) char lds[16384];  // A: 8KB, B: 8KB
  __shared__ float4 sRed[128][2];
  int tid = threadIdx.x;
  int wave = tid >> 6, lane = tid & 63;
  int wm = wave >> 1, wn = wave & 1;
  int q = lane >> 4, l15 = lane & 15;
  int g = blockIdx.x;
  int rb = (g & 7) + ((g >> 6) << 3);  // 8 col-blocks of rb share an XCD
  int cbk = (g >> 3) & 7;
  int row0 = rb * 128, n0 = cbk * 128;

  f32x4 acc[4][4];
#pragma unroll
  for (int i = 0; i < 4; ++i)
#pragma unroll
    for (int j = 0; j < 4; ++j)
      acc[i][j] = (f32x4){0.f, 0.f, 0.f, 0.f};

  // waves 0,1 stage Rh16 (groups s0..s0+3); waves 2,3 stage Ch16.
  const unsigned short* gsrc = (wave < 2) ? Rh16 : Ch16;
  int gbase = ((wave < 2) ? row0 : n0) >> 4;
  int s0 = (wave & 1) * 4;
  const unsigned short* gw =
      gsrc + (size_t)(gbase + s0) * 8192 + lane * 8;
  char* lbase = lds + ((wave < 2) ? 0 : 8192) + s0 * 1024;

  for (int kt = 0; kt < 16; ++kt) {
    __syncthreads();
#pragma unroll
    for (int s = 0; s < 4; ++s) {
      __builtin_amdgcn_global_load_lds(
          (const __attribute__((address_space(1))) void*)(gw + (size_t)s * 8192 + kt * 512),
          (__attribute__((address_space(3))) void*)(lbase + s * 1024), 16, 0, 0);
    }
    __syncthreads();

    half8 af[4];
#pragma unroll
    for (int ti = 0; ti < 4; ++ti)
      af[ti] = *(const half8*)(lds + (wm * 4 + ti) * 1024 + lane * 16);
#pragma unroll
    for (int tj = 0; tj < 4; ++tj) {
      half8 b = *(const half8*)(lds + 8192 + (wn * 4 + tj) * 1024 + lane * 16);
#pragma unroll
      for (int ti = 0; ti < 4; ++ti)
        acc[ti][tj] = __builtin_amdgcn_mfma_f32_16x16x32_f16(af[ti], b, acc[ti][tj], 0, 0, 0);
    }
  }

  // Epilogue: d = cn - 2S; per-row top-2 over this wave's 64 cols, then
  // cross-wn merge via sRed.
  float cn[4]; int coln[4];
#pragma unroll
  for (int tj = 0; tj < 4; ++tj) {
    coln[tj] = n0 + wn * 64 + tj * 16 + l15;
    cn[tj] = cnormF[coln[tj]];
  }
#pragma unroll
  for (int ti = 0; ti < 4; ++ti) {
#pragma unroll
    for (int r = 0; r < 4; ++r) {
      float m1 = FLT_MAX, m2 = FLT_MAX;
      int i1 = INT_MAX, i2 = INT_MAX;
#pragma unroll
      for (int tj = 0; tj < 4; ++tj) {
        float v = cn[tj] - 2.0f * acc[ti][tj][r];
        int ix = coln[tj];
        if (v < m1 || (v == m1 && ix < i1)) {
          m2 = m1; i2 = i1; m1 = v; i1 = ix;
        } else if (v < m2 || (v == m2 && ix < i2)) {
          m2 = v; i2 = ix;
        }
      }
#pragma unroll
      for (int mask = 1; mask <= 8; mask <<= 1) {
        float om1 = __shfl_xor(m1, mask, 64);
        int   oi1 = __shfl_xor(i1, mask, 64);
        float om2 = __shfl_xor(m2, mask, 64);
        int   oi2 = __shfl_xor(i2, mask, 64);
        if (om1 < m1 || (om1 == m1 && oi1 < i1)) {
          m2 = m1; i2 = i1; m1 = om1; i1 = oi1;
        } else if (om1 < m2 || (om1 == m2 && oi1 < i2)) {
          m2 = om1; i2 = oi1;
        }
        if (om2 < m1 || (om2 == m1 && oi2 < i1)) {
          m2 = m1; i2 = i1; m1 = om2; i1 = oi2;
        } else if (om2 < m2 || (om2 == m2 && oi2 < i2)) {
          m2 = om2; i2 = oi2;
        }
      }
      if (l15 == 0) {
        int rit = wm * 64 + ti * 16 + q * 4 + r;
        sRed[rit][wn] =
            make_float4(m1, __int_as_float(i1), m2, __int_as_float(i2));
      }
    }
  }
  __syncthreads();

  if (tid < 128) {
    float4 e0 = sRed[tid][0], e1 = sRed[tid][1];
    float v[4] = {e0.x, e0.z, e1.x, e1.z};
    int ix[4] = {__float_as_int(e0.y), __float_as_int(e0.w),
                 __float_as_int(e1.y), __float_as_int(e1.w)};
    float M1 = FLT_MAX, M2 = FLT_MAX;
    int I1 = INT_MAX, I2 = INT_MAX;
#pragma unroll
    for (int p = 0; p < 4; ++p) {
      if (v[p] < M1 || (v[p] == M1 && ix[p] < I1)) {
        M2 = M1; I2 = I1; M1 = v[p]; I1 = ix[p];
      } else if (v[p] < M2 || (v[p] == M2 && ix[p] < I2)) {
        M2 = v[p]; I2 = ix[p];
      }
    }
    cand[(size_t)(row0 + tid) * 8 + cbk] =
        make_float4(M1, __int_as_float(I1), M2, __int_as_float(I2));
  }
}

// ---------------------------------------------------------------------------
// Stage 2: combine 8 chunk top-2s; fp64-refine near-ties (vs fp32 R);
// write id; update residual (row-major R) + staged fp16 Rh16.
// ---------------------------------------------------------------------------
__global__ __launch_bounds__(256) void vq_refine(
    const float* __restrict__ cb, const double* __restrict__ cnorm,
    const float4* __restrict__ cand, float* __restrict__ R,
    unsigned short* __restrict__ Rh16, float* __restrict__ idsF, int layer) {
  __shared__ int sIdx[64][16];
  __shared__ int sCnt[64];
  __shared__ int sBest[64];

  int tid = threadIdx.x;
  int row0 = blockIdx.x * 64;

  if (tid < 64) {
    int row = row0 + tid;
    float v[16]; int ix[16];
#pragma unroll
    for (int c = 0; c < 8; ++c) {
      float4 e = cand[(size_t)row * 8 + c];
      v[2 * c] = e.x;     ix[2 * c] = __float_as_int(e.y);
      v[2 * c + 1] = e.z; ix[2 * c + 1] = __float_as_int(e.w);
    }
    float M = FLT_MAX; int I = INT_MAX;
#pragma unroll
    for (int p = 0; p < 16; ++p)
      if (v[p] < M || (v[p] == M && ix[p] < I)) { M = v[p]; I = ix[p]; }
    int cnt = 0;
#pragma unroll
    for (int p = 0; p < 16; ++p)
      if (v[p] < M + DELTA && cnt < 16) sIdx[tid][cnt++] = ix[p];
    sCnt[tid] = cnt;
    sBest[tid] = I;
  }
  __syncthreads();

  int wave = tid >> 6, lane = tid & 63;
  for (int r = wave * 16; r < wave * 16 + 16; ++r) {
    int cnt = sCnt[r];
    if (cnt < 2) continue;
    double bestD = 1e300; int bestI = INT_MAX;
    const float* rrow = R + (size_t)(row0 + r) * CB;
    for (int c = 0; c < cnt; ++c) {
      int idx = sIdx[r][c];
      const float* crow = cb + (size_t)idx * CB;
      double s = 0.0;
      for (int e = lane; e < CB; e += 64)
        s += (double)rrow[e] * (double)crow[e];
#pragma unroll
      for (int off = 32; off > 0; off >>= 1)
        s += __shfl_xor(s, off, 64);
      double d = cnorm[idx] - 2.0 * s;
      if (d < bestD || (d == bestD && idx < bestI)) { bestD = d; bestI = idx; }
    }
    if (lane == 0) sBest[r] = bestI;
  }
  __syncthreads();

  if (tid < 64)
    idsF[(size_t)(row0 + tid) * NL + layer] = (float)sBest[tid];

  // residual update: 4 elements per thread per iter
  for (int it = tid; it < 64 * (CB / 4); it += 256) {
    int r = it >> 7, dq = (it & 127) * 4;
    int row = row0 + r;
    size_t o = (size_t)row * CB + dq;
    float4 rv = *(const float4*)(R + o);
    const float* crow = cb + (size_t)sBest[r] * CB + dq;
    float nv[4] = {rv.x - crow[0], rv.y - crow[1], rv.z - crow[2], rv.w - crow[3]};
    *(float4*)(R + o) = make_float4(nv[0], nv[1], nv[2], nv[3]);
    size_t so = staged_off(row, dq);  // dq aligned 4 -> one chunk
    *(ushort4*)(Rh16 + so) =
        make_ushort4(f2h(nv[0]), f2h(nv[1]), f2h(nv[2]), f2h(nv[3]));
  }
}

// ---------------------------------------------------------------------------
// recon[b][j] = dec_b[j] + sum_l ids[b][l] * dec_W[l][j]
// ---------------------------------------------------------------------------
__global__ __launch_bounds__(256) void recon_kernel(
    const float* __restrict__ idsF, const float* __restrict__ decW,
    const float* __restrict__ decb, float* __restrict__ recon) {
  int g = blockIdx.x * 256 + threadIdx.x;
  int b = g >> 9, j = g & (CB - 1);
  float s = decb[j];
#pragma unroll
  for (int l = 0; l < NL; ++l)
    s += idsF[(size_t)b * NL + l] * decW[l * CB + j];
  recon[g] = s;
}

extern "C" void kernel_launch(void* const* d_in, const int* in_sizes, int n_in,
                              void* d_out, int out_size, void* d_ws, size_t ws_size,
                              hipStream_t stream) {
  const float* X    = (const float*)d_in[0];
  const float* encW = (const float*)d_in[1];
  const float* encb = (const float*)d_in[2];
  const float* cbs  = (const float*)d_in[3];
  const float* decW = (const float*)d_in[4];
  const float* decb = (const float*)d_in[5];

  float* out = (float*)d_out;
  float* recon = out;
  float* idsF = out + (size_t)BB * CB;

  char* ws = (char*)d_ws;
  float* R = (float*)ws;                     ws += (size_t)BB * CB * 4;        // 32 MB
  unsigned short* Rh16 = (unsigned short*)ws; ws += (size_t)BB * CB * 2;       // 16 MB
  unsigned short* Ch16 = (unsigned short*)ws; ws += (size_t)NL * KC * CB * 2;  // 4 MB
  double* cnorm = (double*)ws;               ws += (size_t)NL * KC * 8;        // 32 KB
  float* cnormF = (float*)ws;                ws += (size_t)NL * KC * 4;        // 16 KB
  float4* cand = (float4*)ws;                ws += (size_t)BB * 8 * 16;        // 2 MB
  unsigned short* WTh = (unsigned short*)ws; ws += (size_t)CB * DIN * 2;       // 1 MB
  unsigned short* WTm = (unsigned short*)ws;                                   // 1 MB

  cbsplit_kernel<<<(NL * KC * CB) / 1024, 256, 0, stream>>>(cbs, Ch16);
  cnorm_kernel<<<(NL * KC) / 4, 256, 0, stream>>>(cbs, cnorm, cnormF);
  wsplit_kernel<<<(CB * DIN / 4) / 256, 256, 0, stream>>>(encW, WTh, WTm);
  enc_gemm<<<(BB / 128) * (CB / 128), 256, 0, stream>>>(X, WTh, WTm, encb, R);
  rsplit_kernel<<<(BB * CB) / 1024, 256, 0, stream>>>(R, Rh16);
  for (int l = 0; l < NL; ++l) {
    const float* cbl = cbs + (size_t)l * KC * CB;
    vq_stage1<<<(BB / 128) * 8, 256, 0, stream>>>(
        Rh16, Ch16 + (size_t)l * KC * CB, cnormF + (size_t)l * KC, cand);
    vq_refine<<<BB / 64, 256, 0, stream>>>(cbl, cnorm + (size_t)l * KC, cand,
                                           R, Rh16, idsF, l);
  }
  recon_kernel<<<(BB * CB) / 256, 256, 0, stream>>>(idsF, decW, decb, recon);
}

// Round 2
// 482.678 us; speedup vs baseline: 1.5252x; 1.1757x over previous
//
#include <hip/hip_runtime.h>
#include <float.h>
#include <limits.h>

// Problem constants
#define BB 16384   // batch rows
#define DIN 1024   // encoder input dim
#define CB 512     // codebook dim
#define KC 1024    // codewords per layer
#define NL 4       // layers

// Refine margin: fp16 1-term distance noise std ~0.022, max ~0.13.
// 0.25 = ~8 sigma AND >= 2x max single-value error (certainty bound).
#define DELTA 0.25f

typedef __attribute__((ext_vector_type(8))) _Float16 half8;
typedef __attribute__((ext_vector_type(8))) short bf16x8;
typedef __attribute__((ext_vector_type(8))) unsigned short us8;
typedef __attribute__((ext_vector_type(4))) float f32x4;

__device__ __forceinline__ unsigned short f2h(float f) {
  _Float16 h = (_Float16)f;  // RTN
  return *(unsigned short*)&h;
}

// fp32 -> bf16 RTNE (inputs are finite random normals; no NaN handling needed)
__device__ __forceinline__ unsigned short f2b(float f) {
  unsigned u = __float_as_uint(f);
  unsigned r = u + 0x7fffu + ((u >> 16) & 1u);
  return (unsigned short)(r >> 16);
}
__device__ __forceinline__ float b2f(unsigned short h) {
  return __uint_as_float(((unsigned)h) << 16);
}

// Staged layout (shorts) for matrix M[rows][512]:
//   off(row,k) = ((row>>4)*16 + (k>>5))*512 + (((k>>3)&3)*16 + (row&15))*8 + (k&7)
// = MFMA A/B fragment lane image; staging = contiguous 1KB loads.
__device__ __forceinline__ size_t staged_off(int row, int k) {
  return ((size_t)(row >> 4) * 16 + (k >> 5)) * 512 +
         (((k >> 3) & 3) * 16 + (row & 15)) * 8 + (k & 7);
}

// Same staged scheme for 1024-wide rows (WT matrices: [512 rows][1024 k]).
__device__ __forceinline__ size_t staged_off_w(int row, int k) {
  return ((size_t)(row >> 4) * 32 + (k >> 5)) * 512 +
         (((k >> 3) & 3) * 16 + (row & 15)) * 8 + (k & 7);
}

// ---------------------------------------------------------------------------
// Codebooks -> fp16, staged layout.
// ---------------------------------------------------------------------------
__global__ __launch_bounds__(256) void cbsplit_kernel(
    const float* __restrict__ cbs, unsigned short* __restrict__ Ch16) {
  int g = (blockIdx.x * 256 + threadIdx.x) * 4;  // flat over NL*KC*CB
  int k = g & (CB - 1);
  int lr = g >> 9;
  int layer = lr >> 10, row = lr & (KC - 1);
  float4 v = *(const float4*)(cbs + g);
  size_t off = (size_t)layer * (KC / 16) * 8192 + staged_off(row, k);
  *(ushort4*)(Ch16 + off) = make_ushort4(f2h(v.x), f2h(v.y), f2h(v.z), f2h(v.w));
}

// ---------------------------------------------------------------------------
// Residual -> fp16, staged layout (after enc_gemm).
// ---------------------------------------------------------------------------
__global__ __launch_bounds__(256) void rsplit_kernel(
    const float* __restrict__ R, unsigned short* __restrict__ Rh16) {
  int g = (blockIdx.x * 256 + threadIdx.x) * 4;
  int k = g & (CB - 1);
  int row = g >> 9;
  float4 v = *(const float4*)(R + g);
  size_t off = staged_off(row, k);
  *(ushort4*)(Rh16 + off) = make_ushort4(f2h(v.x), f2h(v.y), f2h(v.z), f2h(v.w));
}

// ---------------------------------------------------------------------------
// enc_W^T -> bf16 hi/lo split, staged layout. WTh/WTm are [512][1024] staged.
// W is [DIN=1024][CB=512] row-major fp32; we store its transpose.
// ---------------------------------------------------------------------------
__global__ __launch_bounds__(256) void wsplit_kernel(
    const float* __restrict__ W, unsigned short* __restrict__ WTh,
    unsigned short* __restrict__ WTm) {
  int g = blockIdx.x * 256 + threadIdx.x;  // 131072 total
  int n = g >> 8;           // 0..511  (col of W = row of WT)
  int k0 = (g & 255) * 4;   // 0..1020 (row of W), 4-aligned -> same 8-chunk
  ushort4 h4, m4;
  unsigned short* hp = (unsigned short*)&h4;
  unsigned short* mp = (unsigned short*)&m4;
#pragma unroll
  for (int i = 0; i < 4; ++i) {
    float x = W[(size_t)(k0 + i) * CB + n];
    unsigned short h = f2b(x);
    hp[i] = h;
    mp[i] = f2b(x - b2f(h));
  }
  size_t off = staged_off_w(n, k0);
  *(ushort4*)(WTh + off) = h4;
  *(ushort4*)(WTm + off) = m4;
}

// ---------------------------------------------------------------------------
// cnorm[l*KC+k] = ||codebooks[l][k]||^2, fp64 (refine) + fp32 (stage1)
// ---------------------------------------------------------------------------
__global__ __launch_bounds__(256) void cnorm_kernel(
    const float* __restrict__ cbs, double* __restrict__ cnorm,
    float* __restrict__ cnormF) {
  int gw = (blockIdx.x * blockDim.x + threadIdx.x) >> 6;
  int lane = threadIdx.x & 63;
  if (gw >= NL * KC) return;
  const float* row = cbs + (size_t)gw * CB;
  double s = 0.0;
  for (int i = lane; i < CB; i += 64) {
    double v = (double)row[i];
    s += v * v;
  }
#pragma unroll
  for (int off = 32; off > 0; off >>= 1)
    s += __shfl_down(s, off, 64);
  if (lane == 0) { cnorm[gw] = s; cnormF[gw] = (float)s; }
}

// ---------------------------------------------------------------------------
// Encoder GEMM: R = X @ W + b via 2-way bf16 split, 4 cross products on the
// bf16 MFMA pipe. 128x128 tile, BK=32, 4 waves. (Unchanged this round.)
// ---------------------------------------------------------------------------
__global__ __launch_bounds__(256, 2) void enc_gemm(
    const float* __restrict__ X, const unsigned short* __restrict__ WTh,
    const unsigned short* __restrict__ WTm, const float* __restrict__ bias,
    float* __restrict__ R) {
  __shared__ __align__(16) char lds[32768];  // Ah 8K | Am 8K | Bh 8K | Bm 8K
  int tid = threadIdx.x;
  int wave = tid >> 6, lane = tid & 63;
  int wm = wave >> 1, wn = wave & 1;
  int q = lane >> 4, l15 = lane & 15;
  // XCD swizzle: 512 blocks; each XCD gets 16 consecutive row-panels x 4
  // col-blocks -> the 4 blocks sharing an X row-panel are co-resident.
  int swz = (blockIdx.x & 7) * 64 + (blockIdx.x >> 3);
  int rb = swz >> 2, cbk = swz & 3;
  int row0 = rb * 128, n0 = cbk * 128;

  // A staging map: thread -> (local row ar, k-quarter aq)
  int ar = tid >> 1;          // 0..127
  int aq = (tid & 1) * 16;    // 0 or 16
  const float* xsrc = X + (size_t)(row0 + ar) * DIN + aq;
  // A LDS write base (bytes): chunk (ar>>4) of 1KB; within: ((aq/8)*16+r15)*16
  char* aw_h = lds + (ar >> 4) * 1024 + (((aq >> 3) & 3) * 16 + (ar & 15)) * 16;
  char* aw_m = aw_h + 8192;

  f32x4 acc[4][4];
#pragma unroll
  for (int i = 0; i < 4; ++i)
#pragma unroll
    for (int j = 0; j < 4; ++j)
      acc[i][j] = (f32x4){0.f, 0.f, 0.f, 0.f};

  // prologue: load + split k-chunk 0
  float xv[16];
  unsigned short hv[16], mv[16];
#pragma unroll
  for (int j = 0; j < 4; ++j) {
    float4 v = *(const float4*)(xsrc + j * 4);
    xv[4 * j + 0] = v.x; xv[4 * j + 1] = v.y;
    xv[4 * j + 2] = v.z; xv[4 * j + 3] = v.w;
  }
#pragma unroll
  for (int j = 0; j < 16; ++j) {
    unsigned short h = f2b(xv[j]);
    hv[j] = h;
    mv[j] = f2b(xv[j] - b2f(h));
  }

  for (int kt = 0; kt < 32; ++kt) {
    __syncthreads();  // previous iteration's fragment reads done
    // A tiles: ds_write from the regs split during the previous MFMA phase
    us8 h0, h1, m0, m1;
#pragma unroll
    for (int e = 0; e < 8; ++e) {
      h0[e] = (short)hv[e]; h1[e] = (short)hv[8 + e];
      m0[e] = (short)mv[e]; m1[e] = (short)mv[8 + e];
    }
    *(us8*)aw_h = h0; *(us8*)(aw_h + 256) = h1;
    *(us8*)aw_m = m0; *(us8*)(aw_m + 256) = m1;
    // B tiles: each wave stages 4 of the 16 1KB chunks (Bh: 0..7, Bm: 8..15)
#pragma unroll
    for (int i = 0; i < 4; ++i) {
      int c = wave * 4 + i;
      const unsigned short* bsrc = (c < 8) ? WTh : WTm;
      int rg = (n0 >> 4) + (c & 7);
      __builtin_amdgcn_global_load_lds(
          (const __attribute__((address_space(1))) void*)(
              bsrc + ((size_t)rg * 32 + kt) * 512 + lane * 8),
          (__attribute__((address_space(3))) void*)(lds + 16384 + c * 1024),
          16, 0, 0);
    }
    __syncthreads();  // tiles ready (drains lgkm + vm)

    // fragment reads
    bf16x8 ah[4], am[4];
#pragma unroll
    for (int ti = 0; ti < 4; ++ti) {
      ah[ti] = *(const bf16x8*)(lds + (wm * 4 + ti) * 1024 + lane * 16);
      am[ti] = *(const bf16x8*)(lds + 8192 + (wm * 4 + ti) * 1024 + lane * 16);
    }
    // issue next A chunk's global loads; they complete under the MFMAs
    int kn = (kt + 1) & 31;
#pragma unroll
    for (int j = 0; j < 4; ++j) {
      float4 v = *(const float4*)(xsrc + kn * 32 + j * 4);
      xv[4 * j + 0] = v.x; xv[4 * j + 1] = v.y;
      xv[4 * j + 2] = v.z; xv[4 * j + 3] = v.w;
    }
#pragma unroll
    for (int tj = 0; tj < 4; ++tj) {
      bf16x8 bh = *(const bf16x8*)(lds + 16384 + (wn * 4 + tj) * 1024 + lane * 16);
      bf16x8 bm = *(const bf16x8*)(lds + 24576 + (wn * 4 + tj) * 1024 + lane * 16);
#pragma unroll
      for (int ti = 0; ti < 4; ++ti) {
        acc[ti][tj] = __builtin_amdgcn_mfma_f32_16x16x32_bf16(ah[ti], bh, acc[ti][tj], 0, 0, 0);
        acc[ti][tj] = __builtin_amdgcn_mfma_f32_16x16x32_bf16(am[ti], bh, acc[ti][tj], 0, 0, 0);
        acc[ti][tj] = __builtin_amdgcn_mfma_f32_16x16x32_bf16(ah[ti], bm, acc[ti][tj], 0, 0, 0);
        acc[ti][tj] = __builtin_amdgcn_mfma_f32_16x16x32_bf16(am[ti], bm, acc[ti][tj], 0, 0, 0);
      }
    }
    // split next chunk (VALU; overlaps/follows MFMAs, consumed after barrier)
#pragma unroll
    for (int j = 0; j < 16; ++j) {
      unsigned short h = f2b(xv[j]);
      hv[j] = h;
      mv[j] = f2b(xv[j] - b2f(h));
    }
  }

  // Epilogue: verified 16x16 C/D mapping (col = l15, row = q*4 + r)
#pragma unroll
  for (int ti = 0; ti < 4; ++ti) {
#pragma unroll
    for (int tj = 0; tj < 4; ++tj) {
      int col = n0 + wn * 64 + tj * 16 + l15;
      float bv = bias[col];
#pragma unroll
      for (int r = 0; r < 4; ++r) {
        int row = row0 + wm * 64 + ti * 16 + q * 4 + r;
        R[(size_t)row * CB + col] = acc[ti][tj][r] + bv;
      }
    }
  }
}

// ---------------------------------------------------------------------------
// Stage 1: 1-term fp16 MFMA distance GEMM, 128x128 tile, BK=32.
// v2: double-buffered LDS (2x16KB), ONE barrier per K-iter, next tile's
// global_load_lds issued before computing current tile (2-phase pipeline:
// the syncthreads' vmcnt(0) drain lands after compute hid the load latency).
// ---------------------------------------------------------------------------
__global__ __launch_bounds__(256) void vq_stage1(
    const unsigned short* __restrict__ Rh16,
    const unsigned short* __restrict__ Ch16,
    const float* __restrict__ cnormF, float4* __restrict__ cand) {
  __shared__ __align__(16) char lds[32768];  // [2] x (A: 8KB, B: 8KB)
  __shared__ float4 sRed[128][2];
  int tid = threadIdx.x;
  int wave = tid >> 6, lane = tid & 63;
  int wm = wave >> 1, wn = wave & 1;
  int q = lane >> 4, l15 = lane & 15;
  int g = blockIdx.x;
  int rb = (g & 7) + ((g >> 6) << 3);  // 8 col-blocks of rb share an XCD
  int cbk = (g >> 3) & 7;
  int row0 = rb * 128, n0 = cbk * 128;

  f32x4 acc[4][4];
#pragma unroll
  for (int i = 0; i < 4; ++i)
#pragma unroll
    for (int j = 0; j < 4; ++j)
      acc[i][j] = (f32x4){0.f, 0.f, 0.f, 0.f};

  // waves 0,1 stage Rh16 (groups s0..s0+3); waves 2,3 stage Ch16.
  const unsigned short* gsrc = (wave < 2) ? Rh16 : Ch16;
  int gbase = ((wave < 2) ? row0 : n0) >> 4;
  int s0 = (wave & 1) * 4;
  const unsigned short* gw =
      gsrc + (size_t)(gbase + s0) * 8192 + lane * 8;
  char* lbase = lds + ((wave < 2) ? 0 : 8192) + s0 * 1024;

  // prologue: stage K-tile 0 into buffer 0
#pragma unroll
  for (int s = 0; s < 4; ++s) {
    __builtin_amdgcn_global_load_lds(
        (const __attribute__((address_space(1))) void*)(gw + (size_t)s * 8192),
        (__attribute__((address_space(3))) void*)(lbase + s * 1024), 16, 0, 0);
  }
  __syncthreads();  // vmcnt(0) drain: buffer 0 ready

  for (int kt = 0; kt < 16; ++kt) {
    int cur = kt & 1;
    // issue next tile's loads into the other buffer (no one reads it now)
    if (kt < 15) {
#pragma unroll
      for (int s = 0; s < 4; ++s) {
        __builtin_amdgcn_global_load_lds(
            (const __attribute__((address_space(1))) void*)(
                gw + (size_t)s * 8192 + (kt + 1) * 512),
            (__attribute__((address_space(3))) void*)(
                lbase + (cur ^ 1) * 16384 + s * 1024), 16, 0, 0);
      }
    }
    // compute current buffer
    const char* cb0 = lds + cur * 16384;
    half8 af[4];
#pragma unroll
    for (int ti = 0; ti < 4; ++ti)
      af[ti] = *(const half8*)(cb0 + (wm * 4 + ti) * 1024 + lane * 16);
#pragma unroll
    for (int tj = 0; tj < 4; ++tj) {
      half8 b = *(const half8*)(cb0 + 8192 + (wn * 4 + tj) * 1024 + lane * 16);
#pragma unroll
      for (int ti = 0; ti < 4; ++ti)
        acc[ti][tj] = __builtin_amdgcn_mfma_f32_16x16x32_f16(af[ti], b, acc[ti][tj], 0, 0, 0);
    }
    __syncthreads();  // next buffer landed (vmcnt 0) + all reads of cur done
  }

  // Epilogue: d = cn - 2S; per-row top-2 over this wave's 64 cols, then
  // cross-wn merge via sRed.
  float cn[4]; int coln[4];
#pragma unroll
  for (int tj = 0; tj < 4; ++tj) {
    coln[tj] = n0 + wn * 64 + tj * 16 + l15;
    cn[tj] = cnormF[coln[tj]];
  }
#pragma unroll
  for (int ti = 0; ti < 4; ++ti) {
#pragma unroll
    for (int r = 0; r < 4; ++r) {
      float m1 = FLT_MAX, m2 = FLT_MAX;
      int i1 = INT_MAX, i2 = INT_MAX;
#pragma unroll
      for (int tj = 0; tj < 4; ++tj) {
        float v = cn[tj] - 2.0f * acc[ti][tj][r];
        int ix = coln[tj];
        if (v < m1 || (v == m1 && ix < i1)) {
          m2 = m1; i2 = i1; m1 = v; i1 = ix;
        } else if (v < m2 || (v == m2 && ix < i2)) {
          m2 = v; i2 = ix;
        }
      }
#pragma unroll
      for (int mask = 1; mask <= 8; mask <<= 1) {
        float om1 = __shfl_xor(m1, mask, 64);
        int   oi1 = __shfl_xor(i1, mask, 64);
        float om2 = __shfl_xor(m2, mask, 64);
        int   oi2 = __shfl_xor(i2, mask, 64);
        if (om1 < m1 || (om1 == m1 && oi1 < i1)) {
          m2 = m1; i2 = i1; m1 = om1; i1 = oi1;
        } else if (om1 < m2 || (om1 == m2 && oi1 < i2)) {
          m2 = om1; i2 = oi1;
        }
        if (om2 < m1 || (om2 == m1 && oi2 < i1)) {
          m2 = m1; i2 = i1; m1 = om2; i1 = oi2;
        } else if (om2 < m2 || (om2 == m2 && oi2 < i2)) {
          m2 = om2; i2 = oi2;
        }
      }
      if (l15 == 0) {
        int rit = wm * 64 + ti * 16 + q * 4 + r;
        sRed[rit][wn] =
            make_float4(m1, __int_as_float(i1), m2, __int_as_float(i2));
      }
    }
  }
  __syncthreads();

  if (tid < 128) {
    float4 e0 = sRed[tid][0], e1 = sRed[tid][1];
    float v[4] = {e0.x, e0.z, e1.x, e1.z};
    int ix[4] = {__float_as_int(e0.y), __float_as_int(e0.w),
                 __float_as_int(e1.y), __float_as_int(e1.w)};
    float M1 = FLT_MAX, M2 = FLT_MAX;
    int I1 = INT_MAX, I2 = INT_MAX;
#pragma unroll
    for (int p = 0; p < 4; ++p) {
      if (v[p] < M1 || (v[p] == M1 && ix[p] < I1)) {
        M2 = M1; I2 = I1; M1 = v[p]; I1 = ix[p];
      } else if (v[p] < M2 || (v[p] == M2 && ix[p] < I2)) {
        M2 = v[p]; I2 = ix[p];
      }
    }
    cand[(size_t)(row0 + tid) * 8 + cbk] =
        make_float4(M1, __int_as_float(I1), M2, __int_as_float(I2));
  }
}

// ---------------------------------------------------------------------------
// Stage 2: combine 8 chunk top-2s; fp64-refine near-ties (vs fp32 R);
// write id; update residual (row-major R) + staged fp16 Rh16.
// v2: 32 rows/block (512 blocks): 2x TLP, half the serial row walk per wave.
// ---------------------------------------------------------------------------
__global__ __launch_bounds__(256) void vq_refine(
    const float* __restrict__ cb, const double* __restrict__ cnorm,
    const float4* __restrict__ cand, float* __restrict__ R,
    unsigned short* __restrict__ Rh16, float* __restrict__ idsF, int layer) {
  __shared__ int sIdx[32][16];
  __shared__ int sCnt[32];
  __shared__ int sBest[32];

  int tid = threadIdx.x;
  int row0 = blockIdx.x * 32;

  if (tid < 32) {
    int row = row0 + tid;
    float v[16]; int ix[16];
#pragma unroll
    for (int c = 0; c < 8; ++c) {
      float4 e = cand[(size_t)row * 8 + c];
      v[2 * c] = e.x;     ix[2 * c] = __float_as_int(e.y);
      v[2 * c + 1] = e.z; ix[2 * c + 1] = __float_as_int(e.w);
    }
    float M = FLT_MAX; int I = INT_MAX;
#pragma unroll
    for (int p = 0; p < 16; ++p)
      if (v[p] < M || (v[p] == M && ix[p] < I)) { M = v[p]; I = ix[p]; }
    int cnt = 0;
#pragma unroll
    for (int p = 0; p < 16; ++p)
      if (v[p] < M + DELTA && cnt < 16) sIdx[tid][cnt++] = ix[p];
    sCnt[tid] = cnt;
    sBest[tid] = I;
  }
  __syncthreads();

  int wave = tid >> 6, lane = tid & 63;
  for (int r = wave * 8; r < wave * 8 + 8; ++r) {
    int cnt = sCnt[r];
    if (cnt < 2) continue;
    double bestD = 1e300; int bestI = INT_MAX;
    const float* rrow = R + (size_t)(row0 + r) * CB;
    for (int c = 0; c < cnt; ++c) {
      int idx = sIdx[r][c];
      const float* crow = cb + (size_t)idx * CB;
      double s = 0.0;
      for (int e = lane; e < CB; e += 64)
        s += (double)rrow[e] * (double)crow[e];
#pragma unroll
      for (int off = 32; off > 0; off >>= 1)
        s += __shfl_xor(s, off, 64);
      double d = cnorm[idx] - 2.0 * s;
      if (d < bestD || (d == bestD && idx < bestI)) { bestD = d; bestI = idx; }
    }
    if (lane == 0) sBest[r] = bestI;
  }
  __syncthreads();

  if (tid < 32)
    idsF[(size_t)(row0 + tid) * NL + layer] = (float)sBest[tid];

  // residual update: 4 elements per thread per iter
  for (int it = tid; it < 32 * (CB / 4); it += 256) {
    int r = it >> 7, dq = (it & 127) * 4;
    int row = row0 + r;
    size_t o = (size_t)row * CB + dq;
    float4 rv = *(const float4*)(R + o);
    const float* crow = cb + (size_t)sBest[r] * CB + dq;
    float nv[4] = {rv.x - crow[0], rv.y - crow[1], rv.z - crow[2], rv.w - crow[3]};
    *(float4*)(R + o) = make_float4(nv[0], nv[1], nv[2], nv[3]);
    size_t so = staged_off(row, dq);  // dq aligned 4 -> one chunk
    *(ushort4*)(Rh16 + so) =
        make_ushort4(f2h(nv[0]), f2h(nv[1]), f2h(nv[2]), f2h(nv[3]));
  }
}

// ---------------------------------------------------------------------------
// recon[b][j] = dec_b[j] + sum_l ids[b][l] * dec_W[l][j]
// ---------------------------------------------------------------------------
__global__ __launch_bounds__(256) void recon_kernel(
    const float* __restrict__ idsF, const float* __restrict__ decW,
    const float* __restrict__ decb, float* __restrict__ recon) {
  int g = blockIdx.x * 256 + threadIdx.x;
  int b = g >> 9, j = g & (CB - 1);
  float s = decb[j];
#pragma unroll
  for (int l = 0; l < NL; ++l)
    s += idsF[(size_t)b * NL + l] * decW[l * CB + j];
  recon[g] = s;
}

extern "C" void kernel_launch(void* const* d_in, const int* in_sizes, int n_in,
                              void* d_out, int out_size, void* d_ws, size_t ws_size,
                              hipStream_t stream) {
  const float* X    = (const float*)d_in[0];
  const float* encW = (const float*)d_in[1];
  const float* encb = (const float*)d_in[2];
  const float* cbs  = (const float*)d_in[3];
  const float* decW = (const float*)d_in[4];
  const float* decb = (const float*)d_in[5];

  float* out = (float*)d_out;
  float* recon = out;
  float* idsF = out + (size_t)BB * CB;

  char* ws = (char*)d_ws;
  float* R = (float*)ws;                     ws += (size_t)BB * CB * 4;        // 32 MB
  unsigned short* Rh16 = (unsigned short*)ws; ws += (size_t)BB * CB * 2;       // 16 MB
  unsigned short* Ch16 = (unsigned short*)ws; ws += (size_t)NL * KC * CB * 2;  // 4 MB
  double* cnorm = (double*)ws;               ws += (size_t)NL * KC * 8;        // 32 KB
  float* cnormF = (float*)ws;                ws += (size_t)NL * KC * 4;        // 16 KB
  float4* cand = (float4*)ws;                ws += (size_t)BB * 8 * 16;        // 2 MB
  unsigned short* WTh = (unsigned short*)ws; ws += (size_t)CB * DIN * 2;       // 1 MB
  unsigned short* WTm = (unsigned short*)ws;                                   // 1 MB

  cbsplit_kernel<<<(NL * KC * CB) / 1024, 256, 0, stream>>>(cbs, Ch16);
  cnorm_kernel<<<(NL * KC) / 4, 256, 0, stream>>>(cbs, cnorm, cnormF);
  wsplit_kernel<<<(CB * DIN / 4) / 256, 256, 0, stream>>>(encW, WTh, WTm);
  enc_gemm<<<(BB / 128) * (CB / 128), 256, 0, stream>>>(X, WTh, WTm, encb, R);
  rsplit_kernel<<<(BB * CB) / 1024, 256, 0, stream>>>(R, Rh16);
  for (int l = 0; l < NL; ++l) {
    const float* cbl = cbs + (size_t)l * KC * CB;
    vq_stage1<<<(BB / 128) * 8, 256, 0, stream>>>(
        Rh16, Ch16 + (size_t)l * KC * CB, cnormF + (size_t)l * KC, cand);
    vq_refine<<<BB / 32, 256, 0, stream>>>(cbl, cnorm + (size_t)l * KC, cand,
                                           R, Rh16, idsF, l);
  }
  recon_kernel<<<(BB * CB) / 256, 256, 0, stream>>>(idsF, decW, decb, recon);
}

// Round 3
// 445.958 us; speedup vs baseline: 1.6508x; 1.0823x over previous
//
#include <hip/hip_runtime.h>
#include <float.h>
#include <limits.h>

// Problem constants
#define BB 16384   // batch rows
#define DIN 1024   // encoder input dim
#define CB 512     // codebook dim
#define KC 1024    // codewords per layer
#define NL 4       // layers

// Refine margin: fp16 1-term distance noise std ~0.022, max ~0.13.
// 0.25 = ~8 sigma AND >= 2x max single-value error (certainty bound).
#define DELTA 0.25f

typedef __attribute__((ext_vector_type(8))) _Float16 half8;
typedef __attribute__((ext_vector_type(8))) short bf16x8;
typedef __attribute__((ext_vector_type(8))) unsigned short us8;
typedef __attribute__((ext_vector_type(4))) float f32x4;

__device__ __forceinline__ unsigned short f2h(float f) {
  _Float16 h = (_Float16)f;  // RTN
  return *(unsigned short*)&h;
}

// fp32 -> bf16 RTNE (inputs are finite random normals; no NaN handling needed)
__device__ __forceinline__ unsigned short f2b(float f) {
  unsigned u = __float_as_uint(f);
  unsigned r = u + 0x7fffu + ((u >> 16) & 1u);
  return (unsigned short)(r >> 16);
}
__device__ __forceinline__ float b2f(unsigned short h) {
  return __uint_as_float(((unsigned)h) << 16);
}

// Staged layout (shorts) for matrix M[rows][512]:
//   off(row,k) = ((row>>4)*16 + (k>>5))*512 + (((k>>3)&3)*16 + (row&15))*8 + (k&7)
// = MFMA A/B fragment lane image; staging = contiguous 1KB loads.
__device__ __forceinline__ size_t staged_off(int row, int k) {
  return ((size_t)(row >> 4) * 16 + (k >> 5)) * 512 +
         (((k >> 3) & 3) * 16 + (row & 15)) * 8 + (k & 7);
}

// Same staged scheme for 1024-wide rows (WT matrices: [512 rows][1024 k]).
__device__ __forceinline__ size_t staged_off_w(int row, int k) {
  return ((size_t)(row >> 4) * 32 + (k >> 5)) * 512 +
         (((k >> 3) & 3) * 16 + (row & 15)) * 8 + (k & 7);
}

// ---------------------------------------------------------------------------
// Codebooks -> fp16, staged layout.
// ---------------------------------------------------------------------------
__global__ __launch_bounds__(256) void cbsplit_kernel(
    const float* __restrict__ cbs, unsigned short* __restrict__ Ch16) {
  int g = (blockIdx.x * 256 + threadIdx.x) * 4;  // flat over NL*KC*CB
  int k = g & (CB - 1);
  int lr = g >> 9;
  int layer = lr >> 10, row = lr & (KC - 1);
  float4 v = *(const float4*)(cbs + g);
  size_t off = (size_t)layer * (KC / 16) * 8192 + staged_off(row, k);
  *(ushort4*)(Ch16 + off) = make_ushort4(f2h(v.x), f2h(v.y), f2h(v.z), f2h(v.w));
}

// ---------------------------------------------------------------------------
// Residual -> fp16, staged layout (after enc_gemm).
// ---------------------------------------------------------------------------
__global__ __launch_bounds__(256) void rsplit_kernel(
    const float* __restrict__ R, unsigned short* __restrict__ Rh16) {
  int g = (blockIdx.x * 256 + threadIdx.x) * 4;
  int k = g & (CB - 1);
  int row = g >> 9;
  float4 v = *(const float4*)(R + g);
  size_t off = staged_off(row, k);
  *(ushort4*)(Rh16 + off) = make_ushort4(f2h(v.x), f2h(v.y), f2h(v.z), f2h(v.w));
}

// ---------------------------------------------------------------------------
// enc_W^T -> bf16 hi/lo split, staged layout. WTh/WTm are [512][1024] staged.
// W is [DIN=1024][CB=512] row-major fp32; we store its transpose.
// ---------------------------------------------------------------------------
__global__ __launch_bounds__(256) void wsplit_kernel(
    const float* __restrict__ W, unsigned short* __restrict__ WTh,
    unsigned short* __restrict__ WTm) {
  int g = blockIdx.x * 256 + threadIdx.x;  // 131072 total
  int n = g >> 8;           // 0..511  (col of W = row of WT)
  int k0 = (g & 255) * 4;   // 0..1020 (row of W), 4-aligned -> same 8-chunk
  ushort4 h4, m4;
  unsigned short* hp = (unsigned short*)&h4;
  unsigned short* mp = (unsigned short*)&m4;
#pragma unroll
  for (int i = 0; i < 4; ++i) {
    float x = W[(size_t)(k0 + i) * CB + n];
    unsigned short h = f2b(x);
    hp[i] = h;
    mp[i] = f2b(x - b2f(h));
  }
  size_t off = staged_off_w(n, k0);
  *(ushort4*)(WTh + off) = h4;
  *(ushort4*)(WTm + off) = m4;
}

// ---------------------------------------------------------------------------
// cnorm[l*KC+k] = ||codebooks[l][k]||^2, fp64 (refine) + fp32 (stage1)
// ---------------------------------------------------------------------------
__global__ __launch_bounds__(256) void cnorm_kernel(
    const float* __restrict__ cbs, double* __restrict__ cnorm,
    float* __restrict__ cnormF) {
  int gw = (blockIdx.x * blockDim.x + threadIdx.x) >> 6;
  int lane = threadIdx.x & 63;
  if (gw >= NL * KC) return;
  const float* row = cbs + (size_t)gw * CB;
  double s = 0.0;
  for (int i = lane; i < CB; i += 64) {
    double v = (double)row[i];
    s += v * v;
  }
#pragma unroll
  for (int off = 32; off > 0; off >>= 1)
    s += __shfl_down(s, off, 64);
  if (lane == 0) { cnorm[gw] = s; cnormF[gw] = (float)s; }
}

// ---------------------------------------------------------------------------
// Encoder GEMM: R = X @ W + b via 2-way bf16 split, 4 cross products on the
// bf16 MFMA pipe. 128x128 tile, BK=32, 4 waves.
// v3: FULL double-buffer (A+B, 2x32KB). One barrier per K-step; B(kt+1)
// global_load_lds + A(kt+1) ds_write land in the alternate buffer while
// MFMAs run on the current one -> staging latency hidden (was: B loads
// issued between two adjacent barriers = full latency exposed 32x).
// ---------------------------------------------------------------------------
__global__ __launch_bounds__(256, 2) void enc_gemm(
    const float* __restrict__ X, const unsigned short* __restrict__ WTh,
    const unsigned short* __restrict__ WTm, const float* __restrict__ bias,
    float* __restrict__ R) {
  __shared__ __align__(16) char lds[65536];  // [2] x (Ah 8K|Am 8K|Bh 8K|Bm 8K)
  int tid = threadIdx.x;
  int wave = tid >> 6, lane = tid & 63;
  int wm = wave >> 1, wn = wave & 1;
  int q = lane >> 4, l15 = lane & 15;
  // XCD swizzle: 512 blocks; each XCD gets 16 consecutive row-panels x 4
  // col-blocks -> the 4 blocks sharing an X row-panel are co-resident.
  int swz = (blockIdx.x & 7) * 64 + (blockIdx.x >> 3);
  int rb = swz >> 2, cbk = swz & 3;
  int row0 = rb * 128, n0 = cbk * 128;

  // A staging map: thread -> (local row ar, k-quarter aq)
  int ar = tid >> 1;          // 0..127
  int aq = (tid & 1) * 16;    // 0 or 16
  const float* xsrc = X + (size_t)(row0 + ar) * DIN + aq;
  // A LDS write offset within a buffer (bytes)
  int awoff = (ar >> 4) * 1024 + (((aq >> 3) & 3) * 16 + (ar & 15)) * 16;

  f32x4 acc[4][4];
#pragma unroll
  for (int i = 0; i < 4; ++i)
#pragma unroll
    for (int j = 0; j < 4; ++j)
      acc[i][j] = (f32x4){0.f, 0.f, 0.f, 0.f};

  float xv[16];
  unsigned short hv[16], mv[16];

#define LOADX(c)                                         \
  {                                                      \
    _Pragma("unroll") for (int j = 0; j < 4; ++j) {      \
      float4 v = *(const float4*)(xsrc + (c) * 32 + j * 4); \
      xv[4 * j + 0] = v.x; xv[4 * j + 1] = v.y;          \
      xv[4 * j + 2] = v.z; xv[4 * j + 3] = v.w;          \
    }                                                    \
  }
#define SPLITX()                                         \
  {                                                      \
    _Pragma("unroll") for (int j = 0; j < 16; ++j) {     \
      unsigned short h = f2b(xv[j]);                     \
      hv[j] = h;                                         \
      mv[j] = f2b(xv[j] - b2f(h));                       \
    }                                                    \
  }
#define WRITEA(bufbase)                                  \
  {                                                      \
    us8 h0, h1, m0, m1;                                  \
    _Pragma("unroll") for (int e = 0; e < 8; ++e) {      \
      h0[e] = (short)hv[e]; h1[e] = (short)hv[8 + e];    \
      m0[e] = (short)mv[e]; m1[e] = (short)mv[8 + e];    \
    }                                                    \
    *(us8*)(lds + (bufbase) + awoff) = h0;               \
    *(us8*)(lds + (bufbase) + awoff + 256) = h1;         \
    *(us8*)(lds + (bufbase) + awoff + 8192) = m0;        \
    *(us8*)(lds + (bufbase) + awoff + 8192 + 256) = m1;  \
  }
#define ISSUEB(ktile, bufbase)                                               \
  {                                                                          \
    _Pragma("unroll") for (int i = 0; i < 4; ++i) {                          \
      int c = wave * 4 + i;                                                  \
      const unsigned short* bsrc = (c < 8) ? WTh : WTm;                      \
      int rg = (n0 >> 4) + (c & 7);                                         \
      __builtin_amdgcn_global_load_lds(                                      \
          (const __attribute__((address_space(1))) void*)(                   \
              bsrc + ((size_t)rg * 32 + (ktile)) * 512 + lane * 8),          \
          (__attribute__((address_space(3))) void*)(                         \
              lds + (bufbase) + 16384 + c * 1024),                           \
          16, 0, 0);                                                         \
    }                                                                        \
  }

  // prologue: chunk 0 -> buf0; chunk 1 split held in regs
  LOADX(0); SPLITX();
  ISSUEB(0, 0);
  WRITEA(0);
  LOADX(1); SPLITX();
  __syncthreads();  // buf0 ready (vmcnt+lgkm drained)

  for (int kt = 0; kt < 32; ++kt) {
    int cur = kt & 1;
    int nb = (cur ^ 1) << 15;  // alternate buffer base
    if (kt < 31) {
      ISSUEB(kt + 1, nb);  // long-latency first
      WRITEA(nb);          // from regs split last iteration (chunk kt+1)
    }
    if (kt < 30) LOADX(kt + 2);

    const char* cb0 = lds + (cur << 15);
    bf16x8 ah[4], am[4];
#pragma unroll
    for (int ti = 0; ti < 4; ++ti) {
      ah[ti] = *(const bf16x8*)(cb0 + (wm * 4 + ti) * 1024 + lane * 16);
      am[ti] = *(const bf16x8*)(cb0 + 8192 + (wm * 4 + ti) * 1024 + lane * 16);
    }
#pragma unroll
    for (int tj = 0; tj < 4; ++tj) {
      bf16x8 bh = *(const bf16x8*)(cb0 + 16384 + (wn * 4 + tj) * 1024 + lane * 16);
      bf16x8 bm = *(const bf16x8*)(cb0 + 24576 + (wn * 4 + tj) * 1024 + lane * 16);
#pragma unroll
      for (int ti = 0; ti < 4; ++ti)
        acc[ti][tj] = __builtin_amdgcn_mfma_f32_16x16x32_bf16(ah[ti], bh, acc[ti][tj], 0, 0, 0);
#pragma unroll
      for (int ti = 0; ti < 4; ++ti)
        acc[ti][tj] = __builtin_amdgcn_mfma_f32_16x16x32_bf16(am[ti], bh, acc[ti][tj], 0, 0, 0);
#pragma unroll
      for (int ti = 0; ti < 4; ++ti)
        acc[ti][tj] = __builtin_amdgcn_mfma_f32_16x16x32_bf16(ah[ti], bm, acc[ti][tj], 0, 0, 0);
#pragma unroll
      for (int ti = 0; ti < 4; ++ti)
        acc[ti][tj] = __builtin_amdgcn_mfma_f32_16x16x32_bf16(am[ti], bm, acc[ti][tj], 0, 0, 0);
    }
    if (kt < 30) SPLITX();  // chunk kt+2 -> regs for next iteration's WRITEA
    __syncthreads();  // buf nb ready; all reads of cur done
  }

  // Epilogue: verified 16x16 C/D mapping (col = l15, row = q*4 + r)
#pragma unroll
  for (int ti = 0; ti < 4; ++ti) {
#pragma unroll
    for (int tj = 0; tj < 4; ++tj) {
      int col = n0 + wn * 64 + tj * 16 + l15;
      float bv = bias[col];
#pragma unroll
      for (int r = 0; r < 4; ++r) {
        int row = row0 + wm * 64 + ti * 16 + q * 4 + r;
        R[(size_t)row * CB + col] = acc[ti][tj][r] + bv;
      }
    }
  }
#undef LOADX
#undef SPLITX
#undef WRITEA
#undef ISSUEB
}

// ---------------------------------------------------------------------------
// Stage 1: 1-term fp16 MFMA distance GEMM.
// v3: 256x128 tile, each wave owns 64 rows x ALL 128 cols (acc 4x8).
//  - LDS reads: 12 b128 per 32 MFMAs (was 8 per 16) -> 2.2x less LDS traffic
//    per FLOP (stage1 was LDS-port-bound).
//  - Each row's 128 cols in one wave -> per-row top-2 completes in-wave;
//    sRed cross-wave merge phase deleted.
//  - Top-2 via u64 keys (sortable_d<<32 | idx): identical selection
//    semantics (min d, tie -> min idx), ~half the epilogue VALU.
// Double-buffered (2x24KB), one barrier per K-step.
// ---------------------------------------------------------------------------
__global__ __launch_bounds__(256, 2) void vq_stage1(
    const unsigned short* __restrict__ Rh16,
    const unsigned short* __restrict__ Ch16,
    const float* __restrict__ cnormF, float4* __restrict__ cand) {
  __shared__ __align__(16) char lds[49152];  // [2] x (A 16KB | B 8KB)
  int tid = threadIdx.x;
  int wave = tid >> 6, lane = tid & 63;
  int q = lane >> 4, l15 = lane & 15;
  int g = blockIdx.x;
  int rb = (g & 7) + ((g >> 6) << 3);  // 8 col-blocks of rb share an XCD
  int cbk = (g >> 3) & 7;
  int row0 = rb * 256, n0 = cbk * 128;

  f32x4 acc[4][8];
#pragma unroll
  for (int i = 0; i < 4; ++i)
#pragma unroll
    for (int j = 0; j < 8; ++j)
      acc[i][j] = (f32x4){0.f, 0.f, 0.f, 0.f};

  // staging: wave w stages A rowgroups w*4..w*4+3 and B colgroups w*2,w*2+1
  const unsigned short* gA =
      Rh16 + ((size_t)(row0 >> 4) + wave * 4) * 8192 + lane * 8;
  const unsigned short* gB =
      Ch16 + ((size_t)(n0 >> 4) + wave * 2) * 8192 + lane * 8;
  char* lA = lds + wave * 4 * 1024;
  char* lB = lds + 16384 + wave * 2 * 1024;

#define STAGE1_ISSUE(ktile, bufbase)                                         \
  {                                                                          \
    _Pragma("unroll") for (int s = 0; s < 4; ++s) {                          \
      __builtin_amdgcn_global_load_lds(                                      \
          (const __attribute__((address_space(1))) void*)(                   \
              gA + (size_t)s * 8192 + (ktile) * 512),                        \
          (__attribute__((address_space(3))) void*)(lA + (bufbase) + s * 1024), \
          16, 0, 0);                                                         \
    }                                                                        \
    _Pragma("unroll") for (int s = 0; s < 2; ++s) {                          \
      __builtin_amdgcn_global_load_lds(                                      \
          (const __attribute__((address_space(1))) void*)(                   \
              gB + (size_t)s * 8192 + (ktile) * 512),                        \
          (__attribute__((address_space(3))) void*)(lB + (bufbase) + s * 1024), \
          16, 0, 0);                                                         \
    }                                                                        \
  }

  STAGE1_ISSUE(0, 0);
  __syncthreads();  // buf0 ready

  for (int kt = 0; kt < 16; ++kt) {
    int cur = kt & 1;
    if (kt < 15) STAGE1_ISSUE(kt + 1, (cur ^ 1) * 24576);
    const char* ca = lds + cur * 24576;
    const char* cbp = ca + 16384;
    half8 af[4];
#pragma unroll
    for (int ri = 0; ri < 4; ++ri)
      af[ri] = *(const half8*)(ca + (wave * 4 + ri) * 1024 + lane * 16);
#pragma unroll
    for (int tj = 0; tj < 8; ++tj) {
      half8 b = *(const half8*)(cbp + tj * 1024 + lane * 16);
#pragma unroll
      for (int ri = 0; ri < 4; ++ri)
        acc[ri][tj] = __builtin_amdgcn_mfma_f32_16x16x32_f16(af[ri], b, acc[ri][tj], 0, 0, 0);
    }
    __syncthreads();  // next buffer landed + all reads of cur done
  }
#undef STAGE1_ISSUE

  // Epilogue: d = cn - 2S; per-row top-2 over 128 cols, all in-wave.
  float cn[8]; int coln[8];
#pragma unroll
  for (int tj = 0; tj < 8; ++tj) {
    coln[tj] = n0 + tj * 16 + l15;
    cn[tj] = cnormF[coln[tj]];
  }
#pragma unroll
  for (int ri = 0; ri < 4; ++ri) {
#pragma unroll
    for (int r = 0; r < 4; ++r) {
      unsigned long long k1 = ~0ull, k2 = ~0ull;
#pragma unroll
      for (int tj = 0; tj < 8; ++tj) {
        float v = cn[tj] - 2.0f * acc[ri][tj][r];
        unsigned u = __float_as_uint(v);
        u = (u & 0x80000000u) ? ~u : (u | 0x80000000u);
        unsigned long long key =
            ((unsigned long long)u << 32) | (unsigned)coln[tj];
        if (key < k1) { k2 = k1; k1 = key; }
        else if (key < k2) { k2 = key; }
      }
#pragma unroll
      for (int mask = 1; mask <= 8; mask <<= 1) {
        unsigned long long o1 = __shfl_xor(k1, mask, 64);
        unsigned long long o2 = __shfl_xor(k2, mask, 64);
        if (o1 < k1) { k2 = (k1 < o2) ? k1 : o2; k1 = o1; }
        else { k2 = (k2 < o1) ? k2 : o1; }
      }
      if (l15 == 0) {
        unsigned s1 = (unsigned)(k1 >> 32), s2 = (unsigned)(k2 >> 32);
        unsigned b1 = (s1 & 0x80000000u) ? (s1 ^ 0x80000000u) : ~s1;
        unsigned b2 = (s2 & 0x80000000u) ? (s2 ^ 0x80000000u) : ~s2;
        int row = row0 + wave * 64 + ri * 16 + q * 4 + r;
        cand[(size_t)row * 8 + cbk] = make_float4(
            __uint_as_float(b1), __int_as_float((int)(unsigned)k1),
            __uint_as_float(b2), __int_as_float((int)(unsigned)k2));
      }
    }
  }
}

// ---------------------------------------------------------------------------
// Stage 2: combine 8 chunk top-2s; fp64-refine near-ties (vs fp32 R);
// write id; update residual (row-major R) + staged fp16 Rh16.
// 32 rows/block (512 blocks).
// ---------------------------------------------------------------------------
__global__ __launch_bounds__(256) void vq_refine(
    const float* __restrict__ cb, const double* __restrict__ cnorm,
    const float4* __restrict__ cand, float* __restrict__ R,
    unsigned short* __restrict__ Rh16, float* __restrict__ idsF, int layer) {
  __shared__ int sIdx[32][16];
  __shared__ int sCnt[32];
  __shared__ int sBest[32];

  int tid = threadIdx.x;
  int row0 = blockIdx.x * 32;

  if (tid < 32) {
    int row = row0 + tid;
    float v[16]; int ix[16];
#pragma unroll
    for (int c = 0; c < 8; ++c) {
      float4 e = cand[(size_t)row * 8 + c];
      v[2 * c] = e.x;     ix[2 * c] = __float_as_int(e.y);
      v[2 * c + 1] = e.z; ix[2 * c + 1] = __float_as_int(e.w);
    }
    float M = FLT_MAX; int I = INT_MAX;
#pragma unroll
    for (int p = 0; p < 16; ++p)
      if (v[p] < M || (v[p] == M && ix[p] < I)) { M = v[p]; I = ix[p]; }
    int cnt = 0;
#pragma unroll
    for (int p = 0; p < 16; ++p)
      if (v[p] < M + DELTA && cnt < 16) sIdx[tid][cnt++] = ix[p];
    sCnt[tid] = cnt;
    sBest[tid] = I;
  }
  __syncthreads();

  int wave = tid >> 6, lane = tid & 63;
  for (int r = wave * 8; r < wave * 8 + 8; ++r) {
    int cnt = sCnt[r];
    if (cnt < 2) continue;
    double bestD = 1e300; int bestI = INT_MAX;
    const float* rrow = R + (size_t)(row0 + r) * CB;
    for (int c = 0; c < cnt; ++c) {
      int idx = sIdx[r][c];
      const float* crow = cb + (size_t)idx * CB;
      double s = 0.0;
      for (int e = lane; e < CB; e += 64)
        s += (double)rrow[e] * (double)crow[e];
#pragma unroll
      for (int off = 32; off > 0; off >>= 1)
        s += __shfl_xor(s, off, 64);
      double d = cnorm[idx] - 2.0 * s;
      if (d < bestD || (d == bestD && idx < bestI)) { bestD = d; bestI = idx; }
    }
    if (lane == 0) sBest[r] = bestI;
  }
  __syncthreads();

  if (tid < 32)
    idsF[(size_t)(row0 + tid) * NL + layer] = (float)sBest[tid];

  // residual update: 4 elements per thread per iter
  for (int it = tid; it < 32 * (CB / 4); it += 256) {
    int r = it >> 7, dq = (it & 127) * 4;
    int row = row0 + r;
    size_t o = (size_t)row * CB + dq;
    float4 rv = *(const float4*)(R + o);
    const float* crow = cb + (size_t)sBest[r] * CB + dq;
    float nv[4] = {rv.x - crow[0], rv.y - crow[1], rv.z - crow[2], rv.w - crow[3]};
    *(float4*)(R + o) = make_float4(nv[0], nv[1], nv[2], nv[3]);
    size_t so = staged_off(row, dq);  // dq aligned 4 -> one chunk
    *(ushort4*)(Rh16 + so) =
        make_ushort4(f2h(nv[0]), f2h(nv[1]), f2h(nv[2]), f2h(nv[3]));
  }
}

// ---------------------------------------------------------------------------
// recon[b][j] = dec_b[j] + sum_l ids[b][l] * dec_W[l][j]
// ---------------------------------------------------------------------------
__global__ __launch_bounds__(256) void recon_kernel(
    const float* __restrict__ idsF, const float* __restrict__ decW,
    const float* __restrict__ decb, float* __restrict__ recon) {
  int g = blockIdx.x * 256 + threadIdx.x;
  int b = g >> 9, j = g & (CB - 1);
  float s = decb[j];
#pragma unroll
  for (int l = 0; l < NL; ++l)
    s += idsF[(size_t)b * NL + l] * decW[l * CB + j];
  recon[g] = s;
}

extern "C" void kernel_launch(void* const* d_in, const int* in_sizes, int n_in,
                              void* d_out, int out_size, void* d_ws, size_t ws_size,
                              hipStream_t stream) {
  const float* X    = (const float*)d_in[0];
  const float* encW = (const float*)d_in[1];
  const float* encb = (const float*)d_in[2];
  const float* cbs  = (const float*)d_in[3];
  const float* decW = (const float*)d_in[4];
  const float* decb = (const float*)d_in[5];

  float* out = (float*)d_out;
  float* recon = out;
  float* idsF = out + (size_t)BB * CB;

  char* ws = (char*)d_ws;
  float* R = (float*)ws;                     ws += (size_t)BB * CB * 4;        // 32 MB
  unsigned short* Rh16 = (unsigned short*)ws; ws += (size_t)BB * CB * 2;       // 16 MB
  unsigned short* Ch16 = (unsigned short*)ws; ws += (size_t)NL * KC * CB * 2;  // 4 MB
  double* cnorm = (double*)ws;               ws += (size_t)NL * KC * 8;        // 32 KB
  float* cnormF = (float*)ws;                ws += (size_t)NL * KC * 4;        // 16 KB
  float4* cand = (float4*)ws;                ws += (size_t)BB * 8 * 16;        // 2 MB
  unsigned short* WTh = (unsigned short*)ws; ws += (size_t)CB * DIN * 2;       // 1 MB
  unsigned short* WTm = (unsigned short*)ws;                                   // 1 MB

  cbsplit_kernel<<<(NL * KC * CB) / 1024, 256, 0, stream>>>(cbs, Ch16);
  cnorm_kernel<<<(NL * KC) / 4, 256, 0, stream>>>(cbs, cnorm, cnormF);
  wsplit_kernel<<<(CB * DIN / 4) / 256, 256, 0, stream>>>(encW, WTh, WTm);
  enc_gemm<<<(BB / 128) * (CB / 128), 256, 0, stream>>>(X, WTh, WTm, encb, R);
  rsplit_kernel<<<(BB * CB) / 1024, 256, 0, stream>>>(R, Rh16);
  for (int l = 0; l < NL; ++l) {
    const float* cbl = cbs + (size_t)l * KC * CB;
    vq_stage1<<<(BB / 256) * 8, 256, 0, stream>>>(
        Rh16, Ch16 + (size_t)l * KC * CB, cnormF + (size_t)l * KC, cand);
    vq_refine<<<BB / 32, 256, 0, stream>>>(cbl, cnorm + (size_t)l * KC, cand,
                                           R, Rh16, idsF, l);
  }
  recon_kernel<<<(BB * CB) / 256, 256, 0, stream>>>(idsF, decW, decb, recon);
}

// Round 4
// 410.360 us; speedup vs baseline: 1.7940x; 1.0867x over previous
//
#include <hip/hip_runtime.h>
#include <float.h>
#include <limits.h>

// Problem constants
#define BB 16384   // batch rows
#define DIN 1024   // encoder input dim
#define CB 512     // codebook dim
#define KC 1024    // codewords per layer
#define NL 4       // layers

// Refine margin: fp16 1-term distance noise std ~0.022, max ~0.13.
// 0.25 = ~8 sigma AND >= 2x max single-value error (certainty bound).
#define DELTA 0.25f

typedef __attribute__((ext_vector_type(8))) _Float16 half8;
typedef __attribute__((ext_vector_type(8))) short bf16x8;
typedef __attribute__((ext_vector_type(8))) unsigned short us8;
typedef __attribute__((ext_vector_type(4))) float f32x4;

__device__ __forceinline__ unsigned short f2h(float f) {
  _Float16 h = (_Float16)f;  // RTN
  return *(unsigned short*)&h;
}

// fp32 -> bf16 RTNE (inputs are finite random normals; no NaN handling needed)
__device__ __forceinline__ unsigned short f2b(float f) {
  unsigned u = __float_as_uint(f);
  unsigned r = u + 0x7fffu + ((u >> 16) & 1u);
  return (unsigned short)(r >> 16);
}
__device__ __forceinline__ float b2f(unsigned short h) {
  return __uint_as_float(((unsigned)h) << 16);
}

// Staged layout (shorts) for matrix M[rows][512]:
//   off(row,k) = ((row>>4)*16 + (k>>5))*512 + (((k>>3)&3)*16 + (row&15))*8 + (k&7)
// = MFMA A/B fragment lane image; staging = contiguous 1KB loads.
__device__ __forceinline__ size_t staged_off(int row, int k) {
  return ((size_t)(row >> 4) * 16 + (k >> 5)) * 512 +
         (((k >> 3) & 3) * 16 + (row & 15)) * 8 + (k & 7);
}

// Same staged scheme for 1024-wide rows (WT matrices: [512 rows][1024 k]).
__device__ __forceinline__ size_t staged_off_w(int row, int k) {
  return ((size_t)(row >> 4) * 32 + (k >> 5)) * 512 +
         (((k >> 3) & 3) * 16 + (row & 15)) * 8 + (k & 7);
}

// XCD-affinity invariant (perf-only): the 256-row panel p of R/Rh16 is
// produced AND consumed by blocks with blockIdx%8 == p&7 in every kernel
// (enc_gemm, vq_stage1, vq_refine) -> no cross-XCD dirty-L2 reads.

// ---------------------------------------------------------------------------
// Codebooks -> fp16, staged layout.
// ---------------------------------------------------------------------------
__global__ __launch_bounds__(256) void cbsplit_kernel(
    const float* __restrict__ cbs, unsigned short* __restrict__ Ch16) {
  int g = (blockIdx.x * 256 + threadIdx.x) * 4;  // flat over NL*KC*CB
  int k = g & (CB - 1);
  int lr = g >> 9;
  int layer = lr >> 10, row = lr & (KC - 1);
  float4 v = *(const float4*)(cbs + g);
  size_t off = (size_t)layer * (KC / 16) * 8192 + staged_off(row, k);
  *(ushort4*)(Ch16 + off) = make_ushort4(f2h(v.x), f2h(v.y), f2h(v.z), f2h(v.w));
}

// ---------------------------------------------------------------------------
// enc_W^T -> bf16 hi/lo split, staged layout. WTh/WTm are [512][1024] staged.
// W is [DIN=1024][CB=512] row-major fp32; we store its transpose.
// ---------------------------------------------------------------------------
__global__ __launch_bounds__(256) void wsplit_kernel(
    const float* __restrict__ W, unsigned short* __restrict__ WTh,
    unsigned short* __restrict__ WTm) {
  int g = blockIdx.x * 256 + threadIdx.x;  // 131072 total
  int n = g >> 8;           // 0..511  (col of W = row of WT)
  int k0 = (g & 255) * 4;   // 0..1020 (row of W), 4-aligned -> same 8-chunk
  ushort4 h4, m4;
  unsigned short* hp = (unsigned short*)&h4;
  unsigned short* mp = (unsigned short*)&m4;
#pragma unroll
  for (int i = 0; i < 4; ++i) {
    float x = W[(size_t)(k0 + i) * CB + n];
    unsigned short h = f2b(x);
    hp[i] = h;
    mp[i] = f2b(x - b2f(h));
  }
  size_t off = staged_off_w(n, k0);
  *(ushort4*)(WTh + off) = h4;
  *(ushort4*)(WTm + off) = m4;
}

// ---------------------------------------------------------------------------
// cnorm[l*KC+k] = ||codebooks[l][k]||^2, fp64 (refine) + fp32 (stage1)
// ---------------------------------------------------------------------------
__global__ __launch_bounds__(256) void cnorm_kernel(
    const float* __restrict__ cbs, double* __restrict__ cnorm,
    float* __restrict__ cnormF) {
  int gw = (blockIdx.x * blockDim.x + threadIdx.x) >> 6;
  int lane = threadIdx.x & 63;
  if (gw >= NL * KC) return;
  const float* row = cbs + (size_t)gw * CB;
  double s = 0.0;
  for (int i = lane; i < CB; i += 64) {
    double v = (double)row[i];
    s += v * v;
  }
#pragma unroll
  for (int off = 32; off > 0; off >>= 1)
    s += __shfl_down(s, off, 64);
  if (lane == 0) { cnorm[gw] = s; cnormF[gw] = (float)s; }
}

// ---------------------------------------------------------------------------
// Encoder GEMM: R = X @ W + b via bf16 split on the bf16 MFMA pipe.
// v4: 3 products only (hh, mh, hm) -- the mm term is 2^-18-order, same as
// the split's already-dropped residual; 64->48 MFMAs/kt/wave (-25%).
// Fused epilogue also writes Rh16 (staged fp16) -> rsplit kernel deleted.
// XCD swizzle: XCD = (rb>>1)&7 so the 256-row panel p lands on XCD p&7.
// ---------------------------------------------------------------------------
__global__ __launch_bounds__(256, 2) void enc_gemm(
    const float* __restrict__ X, const unsigned short* __restrict__ WTh,
    const unsigned short* __restrict__ WTm, const float* __restrict__ bias,
    float* __restrict__ R, unsigned short* __restrict__ Rh16) {
  __shared__ __align__(16) char lds[65536];  // [2] x (Ah 8K|Am 8K|Bh 8K|Bm 8K)
  int tid = threadIdx.x;
  int wave = tid >> 6, lane = tid & 63;
  int wm = wave >> 1, wn = wave & 1;
  int q = lane >> 4, l15 = lane & 15;
  // bits[0:2]=x(XCD), [3]=rb low bit, [4:5]=cbk, [6:8]=m
  int bx = blockIdx.x;
  int rb = ((bx & 7) << 1) + ((bx >> 3) & 1) + ((bx >> 6) << 4);
  int cbk = (bx >> 4) & 3;
  int row0 = rb * 128, n0 = cbk * 128;

  // A staging map: thread -> (local row ar, k-quarter aq)
  int ar = tid >> 1;          // 0..127
  int aq = (tid & 1) * 16;    // 0 or 16
  const float* xsrc = X + (size_t)(row0 + ar) * DIN + aq;
  // A LDS write offset within a buffer (bytes)
  int awoff = (ar >> 4) * 1024 + (((aq >> 3) & 3) * 16 + (ar & 15)) * 16;

  f32x4 acc[4][4];
#pragma unroll
  for (int i = 0; i < 4; ++i)
#pragma unroll
    for (int j = 0; j < 4; ++j)
      acc[i][j] = (f32x4){0.f, 0.f, 0.f, 0.f};

  float xv[16];
  unsigned short hv[16], mv[16];

#define LOADX(c)                                         \
  {                                                      \
    _Pragma("unroll") for (int j = 0; j < 4; ++j) {      \
      float4 v = *(const float4*)(xsrc + (c) * 32 + j * 4); \
      xv[4 * j + 0] = v.x; xv[4 * j + 1] = v.y;          \
      xv[4 * j + 2] = v.z; xv[4 * j + 3] = v.w;          \
    }                                                    \
  }
#define SPLITX()                                         \
  {                                                      \
    _Pragma("unroll") for (int j = 0; j < 16; ++j) {     \
      unsigned short h = f2b(xv[j]);                     \
      hv[j] = h;                                         \
      mv[j] = f2b(xv[j] - b2f(h));                       \
    }                                                    \
  }
#define WRITEA(bufbase)                                  \
  {                                                      \
    us8 h0, h1, m0, m1;                                  \
    _Pragma("unroll") for (int e = 0; e < 8; ++e) {      \
      h0[e] = (short)hv[e]; h1[e] = (short)hv[8 + e];    \
      m0[e] = (short)mv[e]; m1[e] = (short)mv[8 + e];    \
    }                                                    \
    *(us8*)(lds + (bufbase) + awoff) = h0;               \
    *(us8*)(lds + (bufbase) + awoff + 256) = h1;         \
    *(us8*)(lds + (bufbase) + awoff + 8192) = m0;        \
    *(us8*)(lds + (bufbase) + awoff + 8192 + 256) = m1;  \
  }
#define ISSUEB(ktile, bufbase)                                               \
  {                                                                          \
    _Pragma("unroll") for (int i = 0; i < 4; ++i) {                          \
      int c = wave * 4 + i;                                                  \
      const unsigned short* bsrc = (c < 8) ? WTh : WTm;                      \
      int rg = (n0 >> 4) + (c & 7);                                         \
      __builtin_amdgcn_global_load_lds(                                      \
          (const __attribute__((address_space(1))) void*)(                   \
              bsrc + ((size_t)rg * 32 + (ktile)) * 512 + lane * 8),          \
          (__attribute__((address_space(3))) void*)(                         \
              lds + (bufbase) + 16384 + c * 1024),                           \
          16, 0, 0);                                                         \
    }                                                                        \
  }

  // prologue: chunk 0 -> buf0; chunk 1 split held in regs
  LOADX(0); SPLITX();
  ISSUEB(0, 0);
  WRITEA(0);
  LOADX(1); SPLITX();
  __syncthreads();  // buf0 ready (vmcnt+lgkm drained)

  for (int kt = 0; kt < 32; ++kt) {
    int cur = kt & 1;
    int nb = (cur ^ 1) << 15;  // alternate buffer base
    if (kt < 31) {
      ISSUEB(kt + 1, nb);  // long-latency first
      WRITEA(nb);          // from regs split last iteration (chunk kt+1)
    }
    if (kt < 30) LOADX(kt + 2);

    const char* cb0 = lds + (cur << 15);
    bf16x8 ah[4], am[4];
#pragma unroll
    for (int ti = 0; ti < 4; ++ti) {
      ah[ti] = *(const bf16x8*)(cb0 + (wm * 4 + ti) * 1024 + lane * 16);
      am[ti] = *(const bf16x8*)(cb0 + 8192 + (wm * 4 + ti) * 1024 + lane * 16);
    }
#pragma unroll
    for (int tj = 0; tj < 4; ++tj) {
      bf16x8 bh = *(const bf16x8*)(cb0 + 16384 + (wn * 4 + tj) * 1024 + lane * 16);
      bf16x8 bm = *(const bf16x8*)(cb0 + 24576 + (wn * 4 + tj) * 1024 + lane * 16);
#pragma unroll
      for (int ti = 0; ti < 4; ++ti)
        acc[ti][tj] = __builtin_amdgcn_mfma_f32_16x16x32_bf16(ah[ti], bh, acc[ti][tj], 0, 0, 0);
#pragma unroll
      for (int ti = 0; ti < 4; ++ti)
        acc[ti][tj] = __builtin_amdgcn_mfma_f32_16x16x32_bf16(am[ti], bh, acc[ti][tj], 0, 0, 0);
#pragma unroll
      for (int ti = 0; ti < 4; ++ti)
        acc[ti][tj] = __builtin_amdgcn_mfma_f32_16x16x32_bf16(ah[ti], bm, acc[ti][tj], 0, 0, 0);
      // mm product (am x bm) dropped: 2^-18-order term, below split residual
    }
    if (kt < 30) SPLITX();  // chunk kt+2 -> regs for next iteration's WRITEA
    __syncthreads();  // buf nb ready; all reads of cur done
  }

  // Epilogue: verified 16x16 C/D mapping (col = l15, row = q*4 + r).
  // Writes fp32 R and staged fp16 Rh16 (rsplit fused here).
#pragma unroll
  for (int ti = 0; ti < 4; ++ti) {
#pragma unroll
    for (int tj = 0; tj < 4; ++tj) {
      int col = n0 + wn * 64 + tj * 16 + l15;
      float bv = bias[col];
#pragma unroll
      for (int r = 0; r < 4; ++r) {
        int row = row0 + wm * 64 + ti * 16 + q * 4 + r;
        float val = acc[ti][tj][r] + bv;
        R[(size_t)row * CB + col] = val;
        Rh16[staged_off(row, col)] = f2h(val);
      }
    }
  }
#undef LOADX
#undef SPLITX
#undef WRITEA
#undef ISSUEB
}

// ---------------------------------------------------------------------------
// Stage 1: 1-term fp16 MFMA distance GEMM. 256x128 tile, wave owns
// 64 rows x 128 cols; double-buffered; u64-key top-2 in-wave.
// XCD map: 256-row panel rb has rb&7 == blockIdx%8 (affinity invariant).
// ---------------------------------------------------------------------------
__global__ __launch_bounds__(256, 2) void vq_stage1(
    const unsigned short* __restrict__ Rh16,
    const unsigned short* __restrict__ Ch16,
    const float* __restrict__ cnormF, float4* __restrict__ cand) {
  __shared__ __align__(16) char lds[49152];  // [2] x (A 16KB | B 8KB)
  int tid = threadIdx.x;
  int wave = tid >> 6, lane = tid & 63;
  int q = lane >> 4, l15 = lane & 15;
  int g = blockIdx.x;
  int rb = (g & 7) + ((g >> 6) << 3);  // 8 col-blocks of rb share an XCD
  int cbk = (g >> 3) & 7;
  int row0 = rb * 256, n0 = cbk * 128;

  f32x4 acc[4][8];
#pragma unroll
  for (int i = 0; i < 4; ++i)
#pragma unroll
    for (int j = 0; j < 8; ++j)
      acc[i][j] = (f32x4){0.f, 0.f, 0.f, 0.f};

  // staging: wave w stages A rowgroups w*4..w*4+3 and B colgroups w*2,w*2+1
  const unsigned short* gA =
      Rh16 + ((size_t)(row0 >> 4) + wave * 4) * 8192 + lane * 8;
  const unsigned short* gB =
      Ch16 + ((size_t)(n0 >> 4) + wave * 2) * 8192 + lane * 8;
  char* lA = lds + wave * 4 * 1024;
  char* lB = lds + 16384 + wave * 2 * 1024;

#define STAGE1_ISSUE(ktile, bufbase)                                         \
  {                                                                          \
    _Pragma("unroll") for (int s = 0; s < 4; ++s) {                          \
      __builtin_amdgcn_global_load_lds(                                      \
          (const __attribute__((address_space(1))) void*)(                   \
              gA + (size_t)s * 8192 + (ktile) * 512),                        \
          (__attribute__((address_space(3))) void*)(lA + (bufbase) + s * 1024), \
          16, 0, 0);                                                         \
    }                                                                        \
    _Pragma("unroll") for (int s = 0; s < 2; ++s) {                          \
      __builtin_amdgcn_global_load_lds(                                      \
          (const __attribute__((address_space(1))) void*)(                   \
              gB + (size_t)s * 8192 + (ktile) * 512),                        \
          (__attribute__((address_space(3))) void*)(lB + (bufbase) + s * 1024), \
          16, 0, 0);                                                         \
    }                                                                        \
  }

  STAGE1_ISSUE(0, 0);
  __syncthreads();  // buf0 ready

  for (int kt = 0; kt < 16; ++kt) {
    int cur = kt & 1;
    if (kt < 15) STAGE1_ISSUE(kt + 1, (cur ^ 1) * 24576);
    const char* ca = lds + cur * 24576;
    const char* cbp = ca + 16384;
    half8 af[4];
#pragma unroll
    for (int ri = 0; ri < 4; ++ri)
      af[ri] = *(const half8*)(ca + (wave * 4 + ri) * 1024 + lane * 16);
#pragma unroll
    for (int tj = 0; tj < 8; ++tj) {
      half8 b = *(const half8*)(cbp + tj * 1024 + lane * 16);
#pragma unroll
      for (int ri = 0; ri < 4; ++ri)
        acc[ri][tj] = __builtin_amdgcn_mfma_f32_16x16x32_f16(af[ri], b, acc[ri][tj], 0, 0, 0);
    }
    __syncthreads();  // next buffer landed + all reads of cur done
  }
#undef STAGE1_ISSUE

  // Epilogue: d = cn - 2S; per-row top-2 over 128 cols, all in-wave.
  float cn[8]; int coln[8];
#pragma unroll
  for (int tj = 0; tj < 8; ++tj) {
    coln[tj] = n0 + tj * 16 + l15;
    cn[tj] = cnormF[coln[tj]];
  }
#pragma unroll
  for (int ri = 0; ri < 4; ++ri) {
#pragma unroll
    for (int r = 0; r < 4; ++r) {
      unsigned long long k1 = ~0ull, k2 = ~0ull;
#pragma unroll
      for (int tj = 0; tj < 8; ++tj) {
        float v = cn[tj] - 2.0f * acc[ri][tj][r];
        unsigned u = __float_as_uint(v);
        u = (u & 0x80000000u) ? ~u : (u | 0x80000000u);
        unsigned long long key =
            ((unsigned long long)u << 32) | (unsigned)coln[tj];
        if (key < k1) { k2 = k1; k1 = key; }
        else if (key < k2) { k2 = key; }
      }
#pragma unroll
      for (int mask = 1; mask <= 8; mask <<= 1) {
        unsigned long long o1 = __shfl_xor(k1, mask, 64);
        unsigned long long o2 = __shfl_xor(k2, mask, 64);
        if (o1 < k1) { k2 = (k1 < o2) ? k1 : o2; k1 = o1; }
        else { k2 = (k2 < o1) ? k2 : o1; }
      }
      if (l15 == 0) {
        unsigned s1 = (unsigned)(k1 >> 32), s2 = (unsigned)(k2 >> 32);
        unsigned b1 = (s1 & 0x80000000u) ? (s1 ^ 0x80000000u) : ~s1;
        unsigned b2 = (s2 & 0x80000000u) ? (s2 ^ 0x80000000u) : ~s2;
        int row = row0 + wave * 64 + ri * 16 + q * 4 + r;
        cand[(size_t)row * 8 + cbk] = make_float4(
            __uint_as_float(b1), __int_as_float((int)(unsigned)k1),
            __uint_as_float(b2), __int_as_float((int)(unsigned)k2));
      }
    }
  }
}

// ---------------------------------------------------------------------------
// Stage 2: combine 8 chunk top-2s; fp64-refine near-ties (vs fp32 R);
// write id; update residual (row-major R) + staged fp16 Rh16.
// 32 rows/block (512 blocks). Block remap: XCD = (v>>3)&7 so this block's
// rows live on the same XCD's L2 as enc_gemm/stage1 (affinity invariant).
// ---------------------------------------------------------------------------
__global__ __launch_bounds__(256) void vq_refine(
    const float* __restrict__ cb, const double* __restrict__ cnorm,
    const float4* __restrict__ cand, float* __restrict__ R,
    unsigned short* __restrict__ Rh16, float* __restrict__ idsF, int layer) {
  __shared__ int sIdx[32][16];
  __shared__ int sCnt[32];
  __shared__ int sBest[32];

  int tid = threadIdx.x;
  int b = blockIdx.x;
  // bits [0:2]->v[3:5] (panel), [3:5]->v[0:2], [6:8]->v[6:8]; XCD=b&7=(v>>3)&7
  int v = ((b & 7) << 3) + ((b >> 3) & 7) + ((b >> 6) << 6);
  int row0 = v * 32;

  if (tid < 32) {
    int row = row0 + tid;
    float vv[16]; int ix[16];
#pragma unroll
    for (int c = 0; c < 8; ++c) {
      float4 e = cand[(size_t)row * 8 + c];
      vv[2 * c] = e.x;     ix[2 * c] = __float_as_int(e.y);
      vv[2 * c + 1] = e.z; ix[2 * c + 1] = __float_as_int(e.w);
    }
    float M = FLT_MAX; int I = INT_MAX;
#pragma unroll
    for (int p = 0; p < 16; ++p)
      if (vv[p] < M || (vv[p] == M && ix[p] < I)) { M = vv[p]; I = ix[p]; }
    int cnt = 0;
#pragma unroll
    for (int p = 0; p < 16; ++p)
      if (vv[p] < M + DELTA && cnt < 16) sIdx[tid][cnt++] = ix[p];
    sCnt[tid] = cnt;
    sBest[tid] = I;
  }
  __syncthreads();

  int wave = tid >> 6, lane = tid & 63;
  for (int r = wave * 8; r < wave * 8 + 8; ++r) {
    int cnt = sCnt[r];
    if (cnt < 2) continue;
    double bestD = 1e300; int bestI = INT_MAX;
    const float* rrow = R + (size_t)(row0 + r) * CB;
    for (int c = 0; c < cnt; ++c) {
      int idx = sIdx[r][c];
      const float* crow = cb + (size_t)idx * CB;
      double s = 0.0;
      for (int e = lane; e < CB; e += 64)
        s += (double)rrow[e] * (double)crow[e];
#pragma unroll
      for (int off = 32; off > 0; off >>= 1)
        s += __shfl_xor(s, off, 64);
      double d = cnorm[idx] - 2.0 * s;
      if (d < bestD || (d == bestD && idx < bestI)) { bestD = d; bestI = idx; }
    }
    if (lane == 0) sBest[r] = bestI;
  }
  __syncthreads();

  if (tid < 32)
    idsF[(size_t)(row0 + tid) * NL + layer] = (float)sBest[tid];

  // residual update: 4 elements per thread per iter
  for (int it = tid; it < 32 * (CB / 4); it += 256) {
    int r = it >> 7, dq = (it & 127) * 4;
    int row = row0 + r;
    size_t o = (size_t)row * CB + dq;
    float4 rv = *(const float4*)(R + o);
    const float* crow = cb + (size_t)sBest[r] * CB + dq;
    float nv[4] = {rv.x - crow[0], rv.y - crow[1], rv.z - crow[2], rv.w - crow[3]};
    *(float4*)(R + o) = make_float4(nv[0], nv[1], nv[2], nv[3]);
    size_t so = staged_off(row, dq);  // dq aligned 4 -> one chunk
    *(ushort4*)(Rh16 + so) =
        make_ushort4(f2h(nv[0]), f2h(nv[1]), f2h(nv[2]), f2h(nv[3]));
  }
}

// ---------------------------------------------------------------------------
// recon[b][j] = dec_b[j] + sum_l ids[b][l] * dec_W[l][j]
// ---------------------------------------------------------------------------
__global__ __launch_bounds__(256) void recon_kernel(
    const float* __restrict__ idsF, const float* __restrict__ decW,
    const float* __restrict__ decb, float* __restrict__ recon) {
  int g = blockIdx.x * 256 + threadIdx.x;
  int b = g >> 9, j = g & (CB - 1);
  float s = decb[j];
#pragma unroll
  for (int l = 0; l < NL; ++l)
    s += idsF[(size_t)b * NL + l] * decW[l * CB + j];
  recon[g] = s;
}

extern "C" void kernel_launch(void* const* d_in, const int* in_sizes, int n_in,
                              void* d_out, int out_size, void* d_ws, size_t ws_size,
                              hipStream_t stream) {
  const float* X    = (const float*)d_in[0];
  const float* encW = (const float*)d_in[1];
  const float* encb = (const float*)d_in[2];
  const float* cbs  = (const float*)d_in[3];
  const float* decW = (const float*)d_in[4];
  const float* decb = (const float*)d_in[5];

  float* out = (float*)d_out;
  float* recon = out;
  float* idsF = out + (size_t)BB * CB;

  char* ws = (char*)d_ws;
  float* R = (float*)ws;                     ws += (size_t)BB * CB * 4;        // 32 MB
  unsigned short* Rh16 = (unsigned short*)ws; ws += (size_t)BB * CB * 2;       // 16 MB
  unsigned short* Ch16 = (unsigned short*)ws; ws += (size_t)NL * KC * CB * 2;  // 4 MB
  double* cnorm = (double*)ws;               ws += (size_t)NL * KC * 8;        // 32 KB
  float* cnormF = (float*)ws;                ws += (size_t)NL * KC * 4;        // 16 KB
  float4* cand = (float4*)ws;                ws += (size_t)BB * 8 * 16;        // 2 MB
  unsigned short* WTh = (unsigned short*)ws; ws += (size_t)CB * DIN * 2;       // 1 MB
  unsigned short* WTm = (unsigned short*)ws;                                   // 1 MB

  cbsplit_kernel<<<(NL * KC * CB) / 1024, 256, 0, stream>>>(cbs, Ch16);
  cnorm_kernel<<<(NL * KC) / 4, 256, 0, stream>>>(cbs, cnorm, cnormF);
  wsplit_kernel<<<(CB * DIN / 4) / 256, 256, 0, stream>>>(encW, WTh, WTm);
  enc_gemm<<<(BB / 128) * (CB / 128), 256, 0, stream>>>(X, WTh, WTm, encb, R, Rh16);
  for (int l = 0; l < NL; ++l) {
    const float* cbl = cbs + (size_t)l * KC * CB;
    vq_stage1<<<(BB / 256) * 8, 256, 0, stream>>>(
        Rh16, Ch16 + (size_t)l * KC * CB, cnormF + (size_t)l * KC, cand);
    vq_refine<<<BB / 32, 256, 0, stream>>>(cbl, cnorm + (size_t)l * KC, cand,
                                           R, Rh16, idsF, l);
  }
  recon_kernel<<<(BB * CB) / 256, 256, 0, stream>>>(idsF, decW, decb, recon);
}

// Round 5
// 384.978 us; speedup vs baseline: 1.9123x; 1.0659x over previous
//
#include <hip/hip_runtime.h>
#include <float.h>
#include <limits.h>

// Problem constants
#define BB 16384   // batch rows
#define DIN 1024   // encoder input dim
#define CB 512     // codebook dim
#define KC 1024    // codewords per layer
#define NL 4       // layers

// Refine margin: fp16 1-term distance noise std ~0.022, max ~0.13.
// 0.25 = ~8 sigma AND >= 2x max single-value error (certainty bound).
#define DELTA 0.25f

typedef __attribute__((ext_vector_type(8))) _Float16 half8;
typedef __attribute__((ext_vector_type(8))) short bf16x8;
typedef __attribute__((ext_vector_type(8))) unsigned short us8;
typedef __attribute__((ext_vector_type(4))) float f32x4;

__device__ __forceinline__ unsigned short f2h(float f) {
  _Float16 h = (_Float16)f;  // RTN
  return *(unsigned short*)&h;
}

// fp32 -> bf16 RTNE (host-side tables / wsplit only)
__device__ __forceinline__ unsigned short f2b(float f) {
  unsigned u = __float_as_uint(f);
  unsigned r = u + 0x7fffu + ((u >> 16) & 1u);
  return (unsigned short)(r >> 16);
}
__device__ __forceinline__ float b2f(unsigned short h) {
  return __uint_as_float(((unsigned)h) << 16);
}

// HW packed bf16 convert: dst.lo = bf16(a), dst.hi = bf16(b). One VALU op.
__device__ __forceinline__ unsigned cvtpk_bf16(float a, float b) {
  unsigned r;
  asm("v_cvt_pk_bf16_f32 %0, %1, %2" : "=v"(r) : "v"(a), "v"(b));
  return r;
}

// Staged layout (shorts) for matrix M[rows][512]:
//   off(row,k) = ((row>>4)*16 + (k>>5))*512 + (((k>>3)&3)*16 + (row&15))*8 + (k&7)
// = MFMA A/B fragment lane image; staging = contiguous 1KB loads.
__device__ __forceinline__ size_t staged_off(int row, int k) {
  return ((size_t)(row >> 4) * 16 + (k >> 5)) * 512 +
         (((k >> 3) & 3) * 16 + (row & 15)) * 8 + (k & 7);
}

// Same staged scheme for 1024-wide rows (WT matrices: [512 rows][1024 k]).
__device__ __forceinline__ size_t staged_off_w(int row, int k) {
  return ((size_t)(row >> 4) * 32 + (k >> 5)) * 512 +
         (((k >> 3) & 3) * 16 + (row & 15)) * 8 + (k & 7);
}

// XCD-affinity invariant (perf-only): the 256-row panel p of R/Rh16 is
// produced AND consumed by blocks with blockIdx%8 == p&7 in every kernel
// (enc_gemm, vq_stage1, vq_refine) -> no cross-XCD dirty-L2 reads.

// ---------------------------------------------------------------------------
// Codebooks -> fp16, staged layout.
// ---------------------------------------------------------------------------
__global__ __launch_bounds__(256) void cbsplit_kernel(
    const float* __restrict__ cbs, unsigned short* __restrict__ Ch16) {
  int g = (blockIdx.x * 256 + threadIdx.x) * 4;  // flat over NL*KC*CB
  int k = g & (CB - 1);
  int lr = g >> 9;
  int layer = lr >> 10, row = lr & (KC - 1);
  float4 v = *(const float4*)(cbs + g);
  size_t off = (size_t)layer * (KC / 16) * 8192 + staged_off(row, k);
  *(ushort4*)(Ch16 + off) = make_ushort4(f2h(v.x), f2h(v.y), f2h(v.z), f2h(v.w));
}

// ---------------------------------------------------------------------------
// enc_W^T -> bf16 hi/lo split, staged layout. WTh/WTm are [512][1024] staged.
// W is [DIN=1024][CB=512] row-major fp32; we store its transpose.
// ---------------------------------------------------------------------------
__global__ __launch_bounds__(256) void wsplit_kernel(
    const float* __restrict__ W, unsigned short* __restrict__ WTh,
    unsigned short* __restrict__ WTm) {
  int g = blockIdx.x * 256 + threadIdx.x;  // 131072 total
  int n = g >> 8;           // 0..511  (col of W = row of WT)
  int k0 = (g & 255) * 4;   // 0..1020 (row of W), 4-aligned -> same 8-chunk
  ushort4 h4, m4;
  unsigned short* hp = (unsigned short*)&h4;
  unsigned short* mp = (unsigned short*)&m4;
#pragma unroll
  for (int i = 0; i < 4; ++i) {
    float x = W[(size_t)(k0 + i) * CB + n];
    unsigned short h = f2b(x);
    hp[i] = h;
    mp[i] = f2b(x - b2f(h));
  }
  size_t off = staged_off_w(n, k0);
  *(ushort4*)(WTh + off) = h4;
  *(ushort4*)(WTm + off) = m4;
}

// ---------------------------------------------------------------------------
// cnorm[l*KC+k] = ||codebooks[l][k]||^2, fp64 (refine) + fp32 (stage1)
// ---------------------------------------------------------------------------
__global__ __launch_bounds__(256) void cnorm_kernel(
    const float* __restrict__ cbs, double* __restrict__ cnorm,
    float* __restrict__ cnormF) {
  int gw = (blockIdx.x * blockDim.x + threadIdx.x) >> 6;
  int lane = threadIdx.x & 63;
  if (gw >= NL * KC) return;
  const float* row = cbs + (size_t)gw * CB;
  double s = 0.0;
  for (int i = lane; i < CB; i += 64) {
    double v = (double)row[i];
    s += v * v;
  }
#pragma unroll
  for (int off = 32; off > 0; off >>= 1)
    s += __shfl_down(s, off, 64);
  if (lane == 0) { cnorm[gw] = s; cnormF[gw] = (float)s; }
}

// ---------------------------------------------------------------------------
// Encoder GEMM: R = X @ W + b via bf16 split (3 products: hh, mh, hm) on the
// bf16 MFMA pipe. 128x128 tile, BK=32, 4 waves, full A+B double-buffer.
// v5: split via HW v_cvt_pk_bf16_f32 -- packed output IS the LDS image, so
// both the 4-op-per-value RTNE emulation AND the short->us8 repack vanish
// (VALUBusy was 24%: ~700 VALU cyc/wave/kt, split+pack was most of it).
// Fused epilogue writes Rh16. XCD swizzle: 256-row panel p -> XCD p&7.
// ---------------------------------------------------------------------------
__global__ __launch_bounds__(256, 2) void enc_gemm(
    const float* __restrict__ X, const unsigned short* __restrict__ WTh,
    const unsigned short* __restrict__ WTm, const float* __restrict__ bias,
    float* __restrict__ R, unsigned short* __restrict__ Rh16) {
  __shared__ __align__(16) char lds[65536];  // [2] x (Ah 8K|Am 8K|Bh 8K|Bm 8K)
  int tid = threadIdx.x;
  int wave = tid >> 6, lane = tid & 63;
  int wm = wave >> 1, wn = wave & 1;
  int q = lane >> 4, l15 = lane & 15;
  // bits[0:2]=x(XCD), [3]=rb low bit, [4:5]=cbk, [6:8]=m
  int bx = blockIdx.x;
  int rb = ((bx & 7) << 1) + ((bx >> 3) & 1) + ((bx >> 6) << 4);
  int cbk = (bx >> 4) & 3;
  int row0 = rb * 128, n0 = cbk * 128;

  // A staging map: thread -> (local row ar, k-quarter aq)
  int ar = tid >> 1;          // 0..127
  int aq = (tid & 1) * 16;    // 0 or 16
  const float* xsrc = X + (size_t)(row0 + ar) * DIN + aq;
  // A LDS write offset within a buffer (bytes)
  int awoff = (ar >> 4) * 1024 + (((aq >> 3) & 3) * 16 + (ar & 15)) * 16;

  f32x4 acc[4][4];
#pragma unroll
  for (int i = 0; i < 4; ++i)
#pragma unroll
    for (int j = 0; j < 4; ++j)
      acc[i][j] = (f32x4){0.f, 0.f, 0.f, 0.f};

  float xv[16];
  unsigned hp[8], mp[8];  // packed bf16 pairs: lo = even elem, hi = odd elem

#define LOADX(c)                                         \
  {                                                      \
    _Pragma("unroll") for (int j = 0; j < 4; ++j) {      \
      float4 v = *(const float4*)(xsrc + (c) * 32 + j * 4); \
      xv[4 * j + 0] = v.x; xv[4 * j + 1] = v.y;          \
      xv[4 * j + 2] = v.z; xv[4 * j + 3] = v.w;          \
    }                                                    \
  }
#define SPLITX()                                            \
  {                                                         \
    _Pragma("unroll") for (int j = 0; j < 8; ++j) {         \
      float x0 = xv[2 * j], x1 = xv[2 * j + 1];             \
      unsigned h = cvtpk_bf16(x0, x1);                      \
      float h0 = __uint_as_float(h << 16);                  \
      float h1 = __uint_as_float(h & 0xffff0000u);          \
      hp[j] = h;                                            \
      mp[j] = cvtpk_bf16(x0 - h0, x1 - h1);                 \
    }                                                       \
  }
#define WRITEA(bufbase)                                                     \
  {                                                                         \
    *(uint4*)(lds + (bufbase) + awoff) =                                    \
        make_uint4(hp[0], hp[1], hp[2], hp[3]);                             \
    *(uint4*)(lds + (bufbase) + awoff + 256) =                              \
        make_uint4(hp[4], hp[5], hp[6], hp[7]);                             \
    *(uint4*)(lds + (bufbase) + awoff + 8192) =                             \
        make_uint4(mp[0], mp[1], mp[2], mp[3]);                             \
    *(uint4*)(lds + (bufbase) + awoff + 8192 + 256) =                       \
        make_uint4(mp[4], mp[5], mp[6], mp[7]);                             \
  }
#define ISSUEB(ktile, bufbase)                                               \
  {                                                                          \
    _Pragma("unroll") for (int i = 0; i < 4; ++i) {                          \
      int c = wave * 4 + i;                                                  \
      const unsigned short* bsrc = (c < 8) ? WTh : WTm;                      \
      int rg = (n0 >> 4) + (c & 7);                                         \
      __builtin_amdgcn_global_load_lds(                                      \
          (const __attribute__((address_space(1))) void*)(                   \
              bsrc + ((size_t)rg * 32 + (ktile)) * 512 + lane * 8),          \
          (__attribute__((address_space(3))) void*)(                         \
              lds + (bufbase) + 16384 + c * 1024),                           \
          16, 0, 0);                                                         \
    }                                                                        \
  }

  // prologue: chunk 0 -> buf0; chunk 1 split held in regs
  LOADX(0); SPLITX();
  ISSUEB(0, 0);
  WRITEA(0);
  LOADX(1); SPLITX();
  __syncthreads();  // buf0 ready (vmcnt+lgkm drained)

  for (int kt = 0; kt < 32; ++kt) {
    int cur = kt & 1;
    int nb = (cur ^ 1) << 15;  // alternate buffer base
    if (kt < 31) {
      ISSUEB(kt + 1, nb);  // long-latency first
      WRITEA(nb);          // from regs split last iteration (chunk kt+1)
    }
    if (kt < 30) LOADX(kt + 2);

    const char* cb0 = lds + (cur << 15);
    bf16x8 ah[4], am[4];
#pragma unroll
    for (int ti = 0; ti < 4; ++ti) {
      ah[ti] = *(const bf16x8*)(cb0 + (wm * 4 + ti) * 1024 + lane * 16);
      am[ti] = *(const bf16x8*)(cb0 + 8192 + (wm * 4 + ti) * 1024 + lane * 16);
    }
#pragma unroll
    for (int tj = 0; tj < 4; ++tj) {
      bf16x8 bh = *(const bf16x8*)(cb0 + 16384 + (wn * 4 + tj) * 1024 + lane * 16);
      bf16x8 bm = *(const bf16x8*)(cb0 + 24576 + (wn * 4 + tj) * 1024 + lane * 16);
#pragma unroll
      for (int ti = 0; ti < 4; ++ti)
        acc[ti][tj] = __builtin_amdgcn_mfma_f32_16x16x32_bf16(ah[ti], bh, acc[ti][tj], 0, 0, 0);
#pragma unroll
      for (int ti = 0; ti < 4; ++ti)
        acc[ti][tj] = __builtin_amdgcn_mfma_f32_16x16x32_bf16(am[ti], bh, acc[ti][tj], 0, 0, 0);
#pragma unroll
      for (int ti = 0; ti < 4; ++ti)
        acc[ti][tj] = __builtin_amdgcn_mfma_f32_16x16x32_bf16(ah[ti], bm, acc[ti][tj], 0, 0, 0);
      // mm product (am x bm) dropped: 2^-16-order term, below split residual
    }
    if (kt < 30) SPLITX();  // chunk kt+2 -> regs for next iteration's WRITEA
    __syncthreads();  // buf nb ready; all reads of cur done
  }

  // Epilogue: verified 16x16 C/D mapping (col = l15, row = q*4 + r).
  // Writes fp32 R and staged fp16 Rh16 (rsplit fused here).
#pragma unroll
  for (int ti = 0; ti < 4; ++ti) {
#pragma unroll
    for (int tj = 0; tj < 4; ++tj) {
      int col = n0 + wn * 64 + tj * 16 + l15;
      float bv = bias[col];
#pragma unroll
      for (int r = 0; r < 4; ++r) {
        int row = row0 + wm * 64 + ti * 16 + q * 4 + r;
        float val = acc[ti][tj][r] + bv;
        R[(size_t)row * CB + col] = val;
        Rh16[staged_off(row, col)] = f2h(val);
      }
    }
  }
#undef LOADX
#undef SPLITX
#undef WRITEA
#undef ISSUEB
}

// ---------------------------------------------------------------------------
// Stage 1: 1-term fp16 MFMA distance GEMM. 256x128 tile, wave owns
// 64 rows x 128 cols; double-buffered; u64-key top-2 in-wave.
// XCD map: 256-row panel rb has rb&7 == blockIdx%8 (affinity invariant).
// ---------------------------------------------------------------------------
__global__ __launch_bounds__(256, 2) void vq_stage1(
    const unsigned short* __restrict__ Rh16,
    const unsigned short* __restrict__ Ch16,
    const float* __restrict__ cnormF, float4* __restrict__ cand) {
  __shared__ __align__(16) char lds[49152];  // [2] x (A 16KB | B 8KB)
  int tid = threadIdx.x;
  int wave = tid >> 6, lane = tid & 63;
  int q = lane >> 4, l15 = lane & 15;
  int g = blockIdx.x;
  int rb = (g & 7) + ((g >> 6) << 3);  // 8 col-blocks of rb share an XCD
  int cbk = (g >> 3) & 7;
  int row0 = rb * 256, n0 = cbk * 128;

  f32x4 acc[4][8];
#pragma unroll
  for (int i = 0; i < 4; ++i)
#pragma unroll
    for (int j = 0; j < 8; ++j)
      acc[i][j] = (f32x4){0.f, 0.f, 0.f, 0.f};

  // staging: wave w stages A rowgroups w*4..w*4+3 and B colgroups w*2,w*2+1
  const unsigned short* gA =
      Rh16 + ((size_t)(row0 >> 4) + wave * 4) * 8192 + lane * 8;
  const unsigned short* gB =
      Ch16 + ((size_t)(n0 >> 4) + wave * 2) * 8192 + lane * 8;
  char* lA = lds + wave * 4 * 1024;
  char* lB = lds + 16384 + wave * 2 * 1024;

#define STAGE1_ISSUE(ktile, bufbase)                                         \
  {                                                                          \
    _Pragma("unroll") for (int s = 0; s < 4; ++s) {                          \
      __builtin_amdgcn_global_load_lds(                                      \
          (const __attribute__((address_space(1))) void*)(                   \
              gA + (size_t)s * 8192 + (ktile) * 512),                        \
          (__attribute__((address_space(3))) void*)(lA + (bufbase) + s * 1024), \
          16, 0, 0);                                                         \
    }                                                                        \
    _Pragma("unroll") for (int s = 0; s < 2; ++s) {                          \
      __builtin_amdgcn_global_load_lds(                                      \
          (const __attribute__((address_space(1))) void*)(                   \
              gB + (size_t)s * 8192 + (ktile) * 512),                        \
          (__attribute__((address_space(3))) void*)(lB + (bufbase) + s * 1024), \
          16, 0, 0);                                                         \
    }                                                                        \
  }

  STAGE1_ISSUE(0, 0);
  __syncthreads();  // buf0 ready

  for (int kt = 0; kt < 16; ++kt) {
    int cur = kt & 1;
    if (kt < 15) STAGE1_ISSUE(kt + 1, (cur ^ 1) * 24576);
    const char* ca = lds + cur * 24576;
    const char* cbp = ca + 16384;
    half8 af[4];
#pragma unroll
    for (int ri = 0; ri < 4; ++ri)
      af[ri] = *(const half8*)(ca + (wave * 4 + ri) * 1024 + lane * 16);
#pragma unroll
    for (int tj = 0; tj < 8; ++tj) {
      half8 b = *(const half8*)(cbp + tj * 1024 + lane * 16);
#pragma unroll
      for (int ri = 0; ri < 4; ++ri)
        acc[ri][tj] = __builtin_amdgcn_mfma_f32_16x16x32_f16(af[ri], b, acc[ri][tj], 0, 0, 0);
    }
    __syncthreads();  // next buffer landed + all reads of cur done
  }
#undef STAGE1_ISSUE

  // Epilogue: d = cn - 2S; per-row top-2 over 128 cols, all in-wave.
  float cn[8]; int coln[8];
#pragma unroll
  for (int tj = 0; tj < 8; ++tj) {
    coln[tj] = n0 + tj * 16 + l15;
    cn[tj] = cnormF[coln[tj]];
  }
#pragma unroll
  for (int ri = 0; ri < 4; ++ri) {
#pragma unroll
    for (int r = 0; r < 4; ++r) {
      unsigned long long k1 = ~0ull, k2 = ~0ull;
#pragma unroll
      for (int tj = 0; tj < 8; ++tj) {
        float v = cn[tj] - 2.0f * acc[ri][tj][r];
        unsigned u = __float_as_uint(v);
        u = (u & 0x80000000u) ? ~u : (u | 0x80000000u);
        unsigned long long key =
            ((unsigned long long)u << 32) | (unsigned)coln[tj];
        if (key < k1) { k2 = k1; k1 = key; }
        else if (key < k2) { k2 = key; }
      }
#pragma unroll
      for (int mask = 1; mask <= 8; mask <<= 1) {
        unsigned long long o1 = __shfl_xor(k1, mask, 64);
        unsigned long long o2 = __shfl_xor(k2, mask, 64);
        if (o1 < k1) { k2 = (k1 < o2) ? k1 : o2; k1 = o1; }
        else { k2 = (k2 < o1) ? k2 : o1; }
      }
      if (l15 == 0) {
        unsigned s1 = (unsigned)(k1 >> 32), s2 = (unsigned)(k2 >> 32);
        unsigned b1 = (s1 & 0x80000000u) ? (s1 ^ 0x80000000u) : ~s1;
        unsigned b2 = (s2 & 0x80000000u) ? (s2 ^ 0x80000000u) : ~s2;
        int row = row0 + wave * 64 + ri * 16 + q * 4 + r;
        cand[(size_t)row * 8 + cbk] = make_float4(
            __uint_as_float(b1), __int_as_float((int)(unsigned)k1),
            __uint_as_float(b2), __int_as_float((int)(unsigned)k2));
      }
    }
  }
}

// ---------------------------------------------------------------------------
// Stage 2: combine 8 chunk top-2s; fp64-refine near-ties (vs fp32 R);
// write id; update residual (row-major R) + staged fp16 Rh16.
// v3: phase 2 flattened to a block-wide (row,cand) worklist processed
// wave-parallel (removes per-wave row-serialization skew); exact selection
// done by a 32-thread rescan of sD with identical (d, tie->idx) semantics.
// 32 rows/block (512 blocks); block remap keeps XCD affinity.
// ---------------------------------------------------------------------------
__global__ __launch_bounds__(256) void vq_refine(
    const float* __restrict__ cb, const double* __restrict__ cnorm,
    const float4* __restrict__ cand, float* __restrict__ R,
    unsigned short* __restrict__ Rh16, float* __restrict__ idsF, int layer) {
  __shared__ int sIdx[32][16];
  __shared__ int sCnt[32];
  __shared__ int sBest[32];
  __shared__ int sPair[512];
  __shared__ int sNP;
  __shared__ double sD[32][16];

  int tid = threadIdx.x;
  int b = blockIdx.x;
  // bits [0:2]->v[3:5] (panel), [3:5]->v[0:2], [6:8]->v[6:8]; XCD=b&7=(v>>3)&7
  int v = ((b & 7) << 3) + ((b >> 3) & 7) + ((b >> 6) << 6);
  int row0 = v * 32;

  if (tid == 0) sNP = 0;
  __syncthreads();

  if (tid < 32) {
    int row = row0 + tid;
    float vv[16]; int ix[16];
#pragma unroll
    for (int c = 0; c < 8; ++c) {
      float4 e = cand[(size_t)row * 8 + c];
      vv[2 * c] = e.x;     ix[2 * c] = __float_as_int(e.y);
      vv[2 * c + 1] = e.z; ix[2 * c + 1] = __float_as_int(e.w);
    }
    float M = FLT_MAX; int I = INT_MAX;
#pragma unroll
    for (int p = 0; p < 16; ++p)
      if (vv[p] < M || (vv[p] == M && ix[p] < I)) { M = vv[p]; I = ix[p]; }
    int cnt = 0;
#pragma unroll
    for (int p = 0; p < 16; ++p)
      if (vv[p] < M + DELTA && cnt < 16) sIdx[tid][cnt++] = ix[p];
    sCnt[tid] = cnt;
    sBest[tid] = I;
    if (cnt >= 2) {
      int base = atomicAdd(&sNP, cnt);
      for (int c = 0; c < cnt; ++c) sPair[base + c] = (tid << 4) | c;
    }
  }
  __syncthreads();

  int np = sNP;
  int wave = tid >> 6, lane = tid & 63;
  for (int p = wave; p < np; p += 4) {
    int pr = sPair[p];
    int r = pr >> 4, c = pr & 15;
    int idx = sIdx[r][c];
    const float* rrow = R + (size_t)(row0 + r) * CB;
    const float* crow = cb + (size_t)idx * CB;
    double s = 0.0;
#pragma unroll
    for (int e = 0; e < CB; e += 64)
      s += (double)rrow[e + lane] * (double)crow[e + lane];
#pragma unroll
    for (int off = 32; off > 0; off >>= 1)
      s += __shfl_xor(s, off, 64);
    if (lane == 0) sD[r][c] = cnorm[idx] - 2.0 * s;
  }
  __syncthreads();

  if (tid < 32) {
    int cnt = sCnt[tid];
    if (cnt >= 2) {
      double bestD = 1e300; int bestI = INT_MAX;
      for (int c = 0; c < cnt; ++c) {
        double d = sD[tid][c]; int idx = sIdx[tid][c];
        if (d < bestD || (d == bestD && idx < bestI)) { bestD = d; bestI = idx; }
      }
      sBest[tid] = bestI;
    }
    idsF[(size_t)(row0 + tid) * NL + layer] = (float)sBest[tid];
  }
  __syncthreads();

  // residual update: 4 elements per thread per iter
  for (int it = tid; it < 32 * (CB / 4); it += 256) {
    int r = it >> 7, dq = (it & 127) * 4;
    int row = row0 + r;
    size_t o = (size_t)row * CB + dq;
    float4 rv = *(const float4*)(R + o);
    const float* crow = cb + (size_t)sBest[r] * CB + dq;
    float nv[4] = {rv.x - crow[0], rv.y - crow[1], rv.z - crow[2], rv.w - crow[3]};
    *(float4*)(R + o) = make_float4(nv[0], nv[1], nv[2], nv[3]);
    size_t so = staged_off(row, dq);  // dq aligned 4 -> one chunk
    *(ushort4*)(Rh16 + so) =
        make_ushort4(f2h(nv[0]), f2h(nv[1]), f2h(nv[2]), f2h(nv[3]));
  }
}

// ---------------------------------------------------------------------------
// recon[b][j] = dec_b[j] + sum_l ids[b][l] * dec_W[l][j]
// ---------------------------------------------------------------------------
__global__ __launch_bounds__(256) void recon_kernel(
    const float* __restrict__ idsF, const float* __restrict__ decW,
    const float* __restrict__ decb, float* __restrict__ recon) {
  int g = blockIdx.x * 256 + threadIdx.x;
  int b = g >> 9, j = g & (CB - 1);
  float s = decb[j];
#pragma unroll
  for (int l = 0; l < NL; ++l)
    s += idsF[(size_t)b * NL + l] * decW[l * CB + j];
  recon[g] = s;
}

extern "C" void kernel_launch(void* const* d_in, const int* in_sizes, int n_in,
                              void* d_out, int out_size, void* d_ws, size_t ws_size,
                              hipStream_t stream) {
  const float* X    = (const float*)d_in[0];
  const float* encW = (const float*)d_in[1];
  const float* encb = (const float*)d_in[2];
  const float* cbs  = (const float*)d_in[3];
  const float* decW = (const float*)d_in[4];
  const float* decb = (const float*)d_in[5];

  float* out = (float*)d_out;
  float* recon = out;
  float* idsF = out + (size_t)BB * CB;

  char* ws = (char*)d_ws;
  float* R = (float*)ws;                     ws += (size_t)BB * CB * 4;        // 32 MB
  unsigned short* Rh16 = (unsigned short*)ws; ws += (size_t)BB * CB * 2;       // 16 MB
  unsigned short* Ch16 = (unsigned short*)ws; ws += (size_t)NL * KC * CB * 2;  // 4 MB
  double* cnorm = (double*)ws;               ws += (size_t)NL * KC * 8;        // 32 KB
  float* cnormF = (float*)ws;                ws += (size_t)NL * KC * 4;        // 16 KB
  float4* cand = (float4*)ws;                ws += (size_t)BB * 8 * 16;        // 2 MB
  unsigned short* WTh = (unsigned short*)ws; ws += (size_t)CB * DIN * 2;       // 1 MB
  unsigned short* WTm = (unsigned short*)ws;                                   // 1 MB

  cbsplit_kernel<<<(NL * KC * CB) / 1024, 256, 0, stream>>>(cbs, Ch16);
  cnorm_kernel<<<(NL * KC) / 4, 256, 0, stream>>>(cbs, cnorm, cnormF);
  wsplit_kernel<<<(CB * DIN / 4) / 256, 256, 0, stream>>>(encW, WTh, WTm);
  enc_gemm<<<(BB / 128) * (CB / 128), 256, 0, stream>>>(X, WTh, WTm, encb, R, Rh16);
  for (int l = 0; l < NL; ++l) {
    const float* cbl = cbs + (size_t)l * KC * CB;
    vq_stage1<<<(BB / 256) * 8, 256, 0, stream>>>(
        Rh16, Ch16 + (size_t)l * KC * CB, cnormF + (size_t)l * KC, cand);
    vq_refine<<<BB / 32, 256, 0, stream>>>(cbl, cnorm + (size_t)l * KC, cand,
                                           R, Rh16, idsF, l);
  }
  recon_kernel<<<(BB * CB) / 256, 256, 0, stream>>>(idsF, decW, decb, recon);
}